// Round 16
// baseline (7222.088 us; speedup 1.0000x reference)
//
#include <hip/hip_runtime.h>
#include <hip/hip_bf16.h>
#include <stdint.h>

#define N_PTS   65536
#define DIM     512
#define K_CL    256
#define ITERS   25
#define BM      64         // points per block in assign
#define TAU     1e-2f      // ambiguity margin; fast-path err max ~1e-3 << TAU/2

typedef __attribute__((ext_vector_type(8))) short  bf16x8;   // 8 bf16 (4 VGPRs)
typedef __attribute__((ext_vector_type(4))) float  f32x4;

// ---------------- Threefry-2x32 (JAX-exact, 20 rounds) ----------------
__host__ __device__ static inline uint32_t rotl32(uint32_t x, int d) {
  return (x << d) | (x >> (32 - d));
}

__host__ __device__ static inline void tf2x32(uint32_t k0, uint32_t k1,
                                              uint32_t x0, uint32_t x1,
                                              uint32_t* o0, uint32_t* o1) {
  const uint32_t ks0 = k0, ks1 = k1, ks2 = k0 ^ k1 ^ 0x1BD11BDAu;
  uint32_t v0 = x0 + ks0, v1 = x1 + ks1;
#define TF_ROUND(R) { v0 += v1; v1 = rotl32(v1, R); v1 ^= v0; }
  TF_ROUND(13) TF_ROUND(15) TF_ROUND(26) TF_ROUND(6)
  v0 += ks1; v1 += ks2 + 1u;
  TF_ROUND(17) TF_ROUND(29) TF_ROUND(16) TF_ROUND(24)
  v0 += ks2; v1 += ks0 + 2u;
  TF_ROUND(13) TF_ROUND(15) TF_ROUND(26) TF_ROUND(6)
  v0 += ks0; v1 += ks1 + 3u;
  TF_ROUND(17) TF_ROUND(29) TF_ROUND(16) TF_ROUND(24)
  v0 += ks1; v1 += ks2 + 4u;
  TF_ROUND(13) TF_ROUND(15) TF_ROUND(26) TF_ROUND(6)
  v0 += ks2; v1 += ks0 + 5u;
#undef TF_ROUND
  *o0 = v0; *o1 = v1;
}

// Partitionable random_bits (32-bit): bits[i] = y0 ^ y1 of hash(key,(0,i)).
__global__ void genbits_kernel(unsigned long long* __restrict__ keyarr,
                               uint32_t k0, uint32_t k1) {
  int i = blockIdx.x * 256 + threadIdx.x;
  uint32_t y0, y1;
  tf2x32(k0, k1, 0u, (uint32_t)i, &y0, &y1);
  uint32_t bits = y0 ^ y1;
  keyarr[i] = ((unsigned long long)bits << 32) | (uint32_t)i;
}

// ---- Bitonic sort, identical comparison network, split across launches ----
__global__ void bitonic_global_step(unsigned long long* __restrict__ d,
                                    int k, int j) {
  int t = blockIdx.x * 256 + threadIdx.x;   // 0..32767
  int low = t & (j - 1);
  int i   = ((t ^ low) << 1) | low;
  int ixj = i | j;
  bool up = ((i & k) == 0);
  unsigned long long a = d[i], b = d[ixj];
  if ((a > b) == up) { d[i] = b; d[ixj] = a; }
}

__global__ void bitonic_local_start(unsigned long long* __restrict__ d) {
  __shared__ unsigned long long s[2048];
  const int base = blockIdx.x * 2048;
  for (int u = threadIdx.x; u < 2048; u += 1024) s[u] = d[base + u];
  __syncthreads();
  for (int k = 2; k <= 2048; k <<= 1) {
    for (int j = k >> 1; j > 0; j >>= 1) {
      int t = threadIdx.x;
      int low = t & (j - 1);
      int il  = ((t ^ low) << 1) | low;
      int ixj = il | j;
      bool up = (((base + il) & k) == 0);
      unsigned long long a = s[il], b = s[ixj];
      if ((a > b) == up) { s[il] = b; s[ixj] = a; }
      __syncthreads();
    }
  }
  for (int u = threadIdx.x; u < 2048; u += 1024) d[base + u] = s[u];
}

__global__ void bitonic_local(unsigned long long* __restrict__ d, int k) {
  __shared__ unsigned long long s[2048];
  const int base = blockIdx.x * 2048;
  for (int u = threadIdx.x; u < 2048; u += 1024) s[u] = d[base + u];
  __syncthreads();
  for (int j = 1024; j > 0; j >>= 1) {
    int t = threadIdx.x;
    int low = t & (j - 1);
    int il  = ((t ^ low) << 1) | low;
    int ixj = il | j;
    bool up = (((base + il) & k) == 0);
    unsigned long long a = s[il], b = s[ixj];
    if ((a > b) == up) { s[il] = b; s[ixj] = a; }
    __syncthreads();
  }
  for (int u = threadIdx.x; u < 2048; u += 1024) d[base + u] = s[u];
}

__global__ void extract_low_kernel(const unsigned long long* __restrict__ s,
                                   uint32_t* __restrict__ out) {
  int i = blockIdx.x * 256 + threadIdx.x;
  out[i] = (uint32_t)(s[i] & 0xffffffffULL);
}

__global__ void init_centers_kernel(const unsigned long long* __restrict__ sorted2,
                                    const uint32_t* __restrict__ perm1,
                                    const float* __restrict__ x,
                                    float* __restrict__ ctr) {
  int k = blockIdx.x, d = threadIdx.x;
  uint32_t p   = (uint32_t)(sorted2[k] & 0xffffffffULL);
  uint32_t src = perm1[p];
  ctr[k * DIM + d] = x[(size_t)src * DIM + d];
}

// ---------------- bf16 2-way split helpers ----------------
__device__ static inline ushort f2bf(float f) {
  __hip_bfloat16 b = __float2bfloat16(f);
  return *reinterpret_cast<ushort*>(&b);
}
__device__ static inline float bf2f(ushort u) {
  __hip_bfloat16 b = *reinterpret_cast<__hip_bfloat16*>(&u);
  return __bfloat162float(b);
}
__device__ static inline void split2(float v, ushort& h, ushort& m) {
#pragma clang fp contract(off)
  h = f2bf(v);
  float r1 = v - bf2f(h);
  m = f2bf(r1);
}

// ---------------- iteration-0 prep (cnorm + csplit + zero counters) -------
__global__ void prep_kernel(const float* __restrict__ ctr,
                            float* __restrict__ cnorm,
                            int* __restrict__ ambigCount,
                            int* __restrict__ counts,
                            ushort* __restrict__ ch,
                            ushort* __restrict__ cm) {
  __shared__ float row[DIM];
  const int k = blockIdx.x, t = threadIdx.x;
  if (k == 0 && t == 0) *ambigCount = 0;
  if (t == 1) counts[k] = 0;
  row[t]       = ctr[(size_t)k * DIM + t];
  row[t + 256] = ctr[(size_t)k * DIM + t + 256];
  __syncthreads();
#pragma unroll
  for (int u = t; u < DIM; u += 256) {
    ushort h, m;
    split2(row[u], h, m);
    ch[(size_t)k * DIM + u] = h;
    cm[(size_t)k * DIM + u] = m;
  }
  if (t == 0) {
#pragma clang fp contract(off)
    float s = 0.f;
    for (int j = 0; j < DIM; j++) {
      float v = row[j];
      float p = v * v;
      s = s + p;
    }
    cnorm[k] = s;
  }
}

// argmin fold: NaN is minimal; first index wins ties (lexicographic).
__device__ static inline void argmin_pick(float ov, int ok, float& bv, int& bk) {
  bool no = __builtin_isnan(ov), nb = __builtin_isnan(bv);
  bool take;
  if (no != nb)      take = no;
  else if (no)       take = ok < bk;
  else               take = (ov < bv) || (ov == bv && ok < bk);
  if (take) { bv = ov; bk = ok; }
}

// ---- (best, idx, second) triple machinery for margin tracking ----
__device__ static inline bool before3(float a, int ai, float b, int bi) {
  bool na = __builtin_isnan(a), nb = __builtin_isnan(b);
  if (na != nb) return na;
  if (na)       return ai < bi;
  return a < b || (a == b && ai < bi);
}
__device__ static inline float valmin3(float a, float b) {
  if (__builtin_isnan(a) || __builtin_isnan(b)) return __int_as_float(0x7fc00000);
  return fminf(a, b);
}
__device__ static inline void merge3(float ob, int oi, float os,
                                     float& b, int& i, float& s) {
  if (before3(ob, oi, b, i)) { s = valmin3(b, os); b = ob; i = oi; }
  else                        s = valmin3(s, ob);
}

// MFMA distance-GEMM + argmin + margin gate (r15 proven, frozen).
__launch_bounds__(256, 4)
__global__ void assign_mfma_kernel(const float* __restrict__ x,
                                   const ushort* __restrict__ ch,
                                   const ushort* __restrict__ cm,
                                   const float* __restrict__ cnorm,
                                   int* __restrict__ assign,
                                   int* __restrict__ ambigCount,
                                   int* __restrict__ ambigList) {
  __shared__ __align__(16) ushort ah[64][40], am[64][40];
  __shared__ float  redv[4][64];
  __shared__ int    redi[4][64];
  __shared__ float  reds[4][64];

  const int t = threadIdx.x;
  const int w = t >> 6;
  const int lane = t & 63;
  const int m0 = blockIdx.x * BM;
  const int colbase = w * 64;
  const int l15 = lane & 15, l4 = lane >> 4;

  f32x4 acc[4][4];
#pragma unroll
  for (int i = 0; i < 4; i++)
#pragma unroll
    for (int j = 0; j < 4; j++) acc[i][j] = (f32x4)(0.f);

  for (int k0 = 0; k0 < DIM; k0 += 32) {
    __syncthreads();
    {
      int r = t >> 2, ko = (t & 3) * 8;
      const float* src = &x[(size_t)(m0 + r) * DIM + k0 + ko];
      float4 v0 = *reinterpret_cast<const float4*>(src);
      float4 v1 = *reinterpret_cast<const float4*>(src + 4);
      float vv[8] = {v0.x, v0.y, v0.z, v0.w, v1.x, v1.y, v1.z, v1.w};
      bf16x8 vh, vm;
#pragma unroll
      for (int q = 0; q < 8; q++) {
        ushort h, m;
        split2(vv[q], h, m);
        vh[q] = (short)h; vm[q] = (short)m;
      }
      *reinterpret_cast<bf16x8*>(&ah[r][ko]) = vh;
      *reinterpret_cast<bf16x8*>(&am[r][ko]) = vm;
    }
    __syncthreads();

    bf16x8 bh[4], bm_[4];
    {
      size_t rowoff = (size_t)(colbase + l15) * DIM + k0 + l4 * 8;
#pragma unroll
      for (int j = 0; j < 4; j++) {
        size_t off = rowoff + (size_t)j * 16 * DIM;
        bh[j]  = *reinterpret_cast<const bf16x8*>(&ch[off]);
        bm_[j] = *reinterpret_cast<const bf16x8*>(&cm[off]);
      }
    }
#pragma unroll
    for (int i = 0; i < 4; i++) {
      int r = i * 16 + l15, ko = l4 * 8;
      bf16x8 fah = *reinterpret_cast<bf16x8*>(&ah[r][ko]);
      bf16x8 fam = *reinterpret_cast<bf16x8*>(&am[r][ko]);
#pragma unroll
      for (int j = 0; j < 4; j++) {
        acc[i][j] = __builtin_amdgcn_mfma_f32_16x16x32_bf16(fah, bh[j],  acc[i][j], 0, 0, 0);
        acc[i][j] = __builtin_amdgcn_mfma_f32_16x16x32_bf16(fah, bm_[j], acc[i][j], 0, 0, 0);
        acc[i][j] = __builtin_amdgcn_mfma_f32_16x16x32_bf16(fam, bh[j],  acc[i][j], 0, 0, 0);
      }
    }
  }

  // ---- epilogue: d2 = cnorm - 2*dot; (best, idx, second); margin gate ----
  {
#pragma clang fp contract(off)
    float cn[4];
#pragma unroll
    for (int j = 0; j < 4; j++) cn[j] = cnorm[colbase + j * 16 + l15];

#pragma unroll
    for (int i = 0; i < 4; i++) {
#pragma unroll
      for (int reg = 0; reg < 4; reg++) {
        float bb = __int_as_float(0x7f800000);  // +inf
        int   bi = 0x7fffffff;
        float bs = __int_as_float(0x7f800000);
#pragma unroll
        for (int j = 0; j < 4; j++) {
          int col = colbase + j * 16 + l15;
          float d2 = cn[j] - 2.0f * acc[i][j][reg];
          merge3(d2, col, __int_as_float(0x7f800000), bb, bi, bs);
        }
#pragma unroll
        for (int s = 1; s < 16; s <<= 1) {
          float ob = __shfl_xor(bb, s);
          int   oi = __shfl_xor(bi, s);
          float os = __shfl_xor(bs, s);
          merge3(ob, oi, os, bb, bi, bs);
        }
        if (l15 == 0) {
          int row = i * 16 + l4 * 4 + reg;
          redv[w][row] = bb; redi[w][row] = bi; reds[w][row] = bs;
        }
      }
    }
    __syncthreads();
    if (t < 64) {
      float bb = __int_as_float(0x7f800000);
      int   bi = 0x7fffffff;
      float bs = __int_as_float(0x7f800000);
#pragma unroll
      for (int w2 = 0; w2 < 4; w2++)
        merge3(redv[w2][t], redi[w2][t], reds[w2][t], bb, bi, bs);
      assign[m0 + t] = bi;
      float margin = bs - bb;
      if (!(margin > TAU)) {                 // NaN margin also flags
        int pos = atomicAdd(ambigCount, 1);
        if (pos < N_PTS) ambigList[pos] = m0 + t;
      }
    }
  }
}

// Exact recheck of ambiguous points with the r5 bit-exact scheme.
__launch_bounds__(256)
__global__ void refine_kernel(const float* __restrict__ x,
                              const float* __restrict__ ctr,
                              const float* __restrict__ cnorm,
                              const int* __restrict__ ambigList,
                              const int* __restrict__ ambigCount,
                              int* __restrict__ assign) {
  __shared__ float xrow[DIM];
  __shared__ float cs[K_CL][33];
  __shared__ float rv[K_CL];
  __shared__ int   ri[K_CL];
  const int t = threadIdx.x;
  int cnt = *ambigCount; if (cnt > N_PTS) cnt = N_PTS;
  for (int a = blockIdx.x; a < cnt; a += gridDim.x) {
    int pt = ambigList[a];
    __syncthreads();
    for (int u = t; u < DIM; u += 256) xrow[u] = x[(size_t)pt * DIM + u];
    float accA = 0.f, accB = 0.f;
    for (int c = 0; c < 16; c++) {
      __syncthreads();
      for (int u = t; u < K_CL * 32; u += 256) {
        int k = u >> 5, j = u & 31;
        cs[k][j] = ctr[(size_t)k * DIM + c * 32 + j];
      }
      __syncthreads();
      {
#pragma clang fp contract(off)
        float s = (c < 9) ? accA : accB;
        for (int j = 0; j < 32; j++) {
          float pv = xrow[c * 32 + j] * cs[t][j];
          s = s + pv;
        }
        if (c < 9) accA = s; else accB = s;
      }
    }
    float d2;
    {
#pragma clang fp contract(off)
      float dot = accA + accB;
      float tw = 2.0f * dot;
      d2 = cnorm[t] - tw;
    }
    rv[t] = d2; ri[t] = t;
    __syncthreads();
    for (int st = 128; st >= 1; st >>= 1) {
      if (t < st) argmin_pick(rv[t + st], ri[t + st], rv[t], ri[t]);
      __syncthreads();
    }
    if (t == 0) assign[pt] = ri[0];
  }
}

// Counting sort stage 1: per-block histogram (block-major) + cluster totals
// via integer atomics (order-independent -> deterministic).
__global__ void hist_kernel(const int* __restrict__ assign,
                            int* __restrict__ blockHist,
                            int* __restrict__ counts) {
  __shared__ int h[K_CL];
  int b = blockIdx.x, t = threadIdx.x;
  h[t] = 0; __syncthreads();
  int k = assign[b * 256 + t];
  atomicAdd(&h[k], 1);
  __syncthreads();
  blockHist[b * 256 + t] = h[t];
  if (h[t]) atomicAdd(&counts[t], h[t]);
}

// Stage 2 (fused): blocks 0..255 scan per-cluster block-hists; block 256
// scans cluster totals -> clusterStart. Both depend only on hist output.
__global__ void scan2_kernel(int* __restrict__ blockHist,
                             const int* __restrict__ counts,
                             int* __restrict__ clusterStart) {
  __shared__ int v[256];
  int t = threadIdx.x;
  if (blockIdx.x < 256) {
    int k = blockIdx.x;
    int x = blockHist[t * 256 + k];
    v[t] = x;
    __syncthreads();
    for (int s = 1; s < 256; s <<= 1) {
      int add = (t >= s) ? v[t - s] : 0;
      __syncthreads();
      v[t] += add;
      __syncthreads();
    }
    blockHist[t * 256 + k] = v[t] - x;       // exclusive within-cluster prefix
  } else {
    int x = counts[t];
    v[t] = x;
    __syncthreads();
    for (int s = 1; s < 256; s <<= 1) {
      int add = (t >= s) ? v[t - s] : 0;
      __syncthreads();
      v[t] += add;
      __syncthreads();
    }
    clusterStart[t] = v[t] - x;
  }
}

// Stage 3: stable scatter of point indices into cluster-sorted order.
__global__ void scatter_kernel(const int* __restrict__ assign,
                               const int* __restrict__ blockHist,
                               const int* __restrict__ clusterStart,
                               int* __restrict__ sortedIdx) {
  __shared__ int la[256];
  int b = blockIdx.x, t = threadIdx.x;
  int n = b * 256 + t;
  int k = assign[n];
  la[t] = k; __syncthreads();
  int rank = 0;
  for (int u = 0; u < t; u++) rank += (la[u] == k) ? 1 : 0;
  sortedIdx[clusterStart[k] + blockHist[b * 256 + k] + rank] = n;
}

// Stage 4a: per-(cluster, chunk) partial sums, nch chunks per cluster.
__global__ void segsum_part_kernel(const float* __restrict__ x,
                                   const int* __restrict__ sortedIdx,
                                   const int* __restrict__ clusterStart,
                                   const int* __restrict__ counts,
                                   float* __restrict__ part, int nch) {
#pragma clang fp contract(off)
  int k = blockIdx.x / nch;      // cluster
  int c = blockIdx.x - k * nch;  // chunk
  int d = threadIdx.x;
  int start = clusterStart[k], cnt = counts[k];
  int ch = (cnt + nch - 1) / nch;
  int b0 = c * ch;
  int b1 = b0 + ch; if (b1 > cnt) b1 = cnt;
  float s = 0.f;
  for (int i = b0; i < b1; i++) {
    int idx = sortedIdx[start + i];
    s = s + x[(size_t)idx * DIM + d];
  }
  part[((size_t)k * nch + c) * DIM + d] = s;
}

// Stage 4b (last iter): combine chunks ascending, divide -> out.
__global__ void segsum_final_kernel(const float* __restrict__ part,
                                    const int* __restrict__ counts,
                                    float* __restrict__ out, int nch) {
#pragma clang fp contract(off)
  int k = blockIdx.x, d = threadIdx.x;
  float s = 0.f;
  for (int c = 0; c < nch; c++)
    s = s + part[((size_t)k * nch + c) * DIM + d];
  out[k * DIM + d] = s / (float)counts[k];   // cnt==0 -> NaN, matches ref
}

// Stage 4b+prep fused (iters 0..ITERS-2): combine chunks -> next centers,
// split to bf16 planes, cnorm (same strict-sequential order), zero counters.
// 256 blocks x 512 threads.
__global__ void update_kernel(const float* __restrict__ part,
                              int* __restrict__ counts,
                              float* __restrict__ ctrNext,
                              float* __restrict__ cnorm,
                              int* __restrict__ ambigCount,
                              ushort* __restrict__ ch,
                              ushort* __restrict__ cm, int nch) {
  __shared__ float row[DIM];
  const int k = blockIdx.x, t = threadIdx.x;   // 512 threads, t = dim
  {
#pragma clang fp contract(off)
    float s = 0.f;
    for (int c = 0; c < nch; c++)
      s = s + part[((size_t)k * nch + c) * DIM + t];
    float mean = s / (float)counts[k];         // cnt==0 -> NaN, matches ref
    ctrNext[(size_t)k * DIM + t] = mean;
    row[t] = mean;
  }
  {
    ushort h, m;
    split2(row[t], h, m);
    ch[(size_t)k * DIM + t] = h;
    cm[(size_t)k * DIM + t] = m;
  }
  __syncthreads();                             // all reads of counts[k] done
  if (t == 0) {
#pragma clang fp contract(off)
    float s = 0.f;
    for (int j = 0; j < DIM; j++) {
      float v = row[j];
      float p = v * v;
      s = s + p;
    }
    cnorm[k] = s;
  }
  if (t == 1) counts[k] = 0;                   // ready for next hist
  if (t == 2 && k == 0) *ambigCount = 0;
}

// ---------------- host ----------------
static inline void run_sort(unsigned long long* d, hipStream_t stream) {
  bitonic_local_start<<<32, 1024, 0, stream>>>(d);
  for (int k = 4096; k <= 65536; k <<= 1) {
    for (int j = k >> 1; j >= 2048; j >>= 1)
      bitonic_global_step<<<128, 256, 0, stream>>>(d, k, j);
    bitonic_local<<<32, 1024, 0, stream>>>(d, k);
  }
}

extern "C" void kernel_launch(void* const* d_in, const int* in_sizes, int n_in,
                              void* d_out, int out_size, void* d_ws, size_t ws_size,
                              hipStream_t stream) {
  const float* x = (const float*)d_in[0];
  float* out = (float*)d_out;

  char* p = (char*)d_ws;
  size_t used = 0;
  auto alloc = [&](size_t bytes) {
    char* r = p;
    size_t rb = (bytes + 255) & ~(size_t)255;
    p += rb; used += rb;
    return r;
  };
  unsigned long long* keyA = (unsigned long long*)alloc(N_PTS * 8);
  unsigned long long* keyB = (unsigned long long*)alloc(N_PTS * 8);
  uint32_t* perm1          = (uint32_t*)alloc(N_PTS * 4);
  int* assign              = (int*)alloc(N_PTS * 4);
  int* blockHist           = (int*)alloc(K_CL * 256 * 4);
  int* clusterStart        = (int*)alloc(K_CL * 4);
  int* counts              = (int*)alloc(K_CL * 4);
  int* sortedIdx           = (int*)alloc(N_PTS * 4);
  float* ctrA              = (float*)alloc(K_CL * DIM * 4);
  float* ctrB              = (float*)alloc(K_CL * DIM * 4);
  float* cnorm             = (float*)alloc(K_CL * 4);
  ushort* ch               = (ushort*)alloc((size_t)K_CL * DIM * 2);
  ushort* cm               = (ushort*)alloc((size_t)K_CL * DIM * 2);
  int* ambigCount          = (int*)alloc(4);
  int* ambigList           = (int*)alloc(N_PTS * 4);

  // Chunk count for segsum: 64 if workspace allows, else 8.
  const size_t part64 = (size_t)K_CL * 64 * DIM * 4;   // 33.5 MB
  int nch = (ws_size >= used + part64 + 256) ? 64 : 8;
  float* part = (float*)alloc((size_t)K_CL * nch * DIM * 4);

  // Partitionable (foldlike) threefry split: split(key)[j] = hash(key,(0,j)).
  uint32_t k1a, k1b, s1a, s1b;
  tf2x32(0u, 1u, 0u, 0u, &k1a, &k1b);
  tf2x32(0u, 1u, 0u, 1u, &s1a, &s1b);
  uint32_t k2a, k2b, s2a, s2b;
  tf2x32(k1a, k1b, 0u, 0u, &k2a, &k2b);
  tf2x32(k1a, k1b, 0u, 1u, &s2a, &s2b);

  genbits_kernel<<<256, 256, 0, stream>>>(keyA, s1a, s1b);
  run_sort(keyA, stream);
  extract_low_kernel<<<256, 256, 0, stream>>>(keyA, perm1);
  genbits_kernel<<<256, 256, 0, stream>>>(keyB, s2a, s2b);
  run_sort(keyB, stream);
  init_centers_kernel<<<K_CL, DIM, 0, stream>>>(keyB, perm1, x, ctrA);
  prep_kernel<<<K_CL, 256, 0, stream>>>(ctrA, cnorm, ambigCount, counts, ch, cm);

  float* cur = ctrA;
  for (int it = 0; it < ITERS; ++it) {
    assign_mfma_kernel<<<N_PTS / BM, 256, 0, stream>>>(x, ch, cm, cnorm, assign,
                                                       ambigCount, ambigList);
    refine_kernel<<<1024, 256, 0, stream>>>(x, cur, cnorm, ambigList, ambigCount, assign);
    hist_kernel<<<256, 256, 0, stream>>>(assign, blockHist, counts);
    scan2_kernel<<<257, 256, 0, stream>>>(blockHist, counts, clusterStart);
    scatter_kernel<<<256, 256, 0, stream>>>(assign, blockHist, clusterStart, sortedIdx);
    segsum_part_kernel<<<K_CL * nch, DIM, 0, stream>>>(x, sortedIdx, clusterStart,
                                                       counts, part, nch);
    if (it < ITERS - 1) {
      float* next = (it & 1) ? ctrA : ctrB;
      update_kernel<<<K_CL, DIM, 0, stream>>>(part, counts, next, cnorm,
                                              ambigCount, ch, cm, nch);
      cur = next;
    } else {
      segsum_final_kernel<<<K_CL, DIM, 0, stream>>>(part, counts, out, nch);
    }
  }
}

// Round 17
// 6718.478 us; speedup vs baseline: 1.0750x; 1.0750x over previous
//
#include <hip/hip_runtime.h>
#include <hip/hip_bf16.h>
#include <stdint.h>

#define N_PTS   65536
#define DIM     512
#define K_CL    256
#define ITERS   25
#define BM      64         // points per block in assign
#define TAU     1e-2f      // ambiguity margin; fast-path err max ~1e-3 << TAU/2

typedef __attribute__((ext_vector_type(8))) short  bf16x8;   // 8 bf16 (4 VGPRs)
typedef __attribute__((ext_vector_type(4))) float  f32x4;

// ---------------- Threefry-2x32 (JAX-exact, 20 rounds) ----------------
__host__ __device__ static inline uint32_t rotl32(uint32_t x, int d) {
  return (x << d) | (x >> (32 - d));
}

__host__ __device__ static inline void tf2x32(uint32_t k0, uint32_t k1,
                                              uint32_t x0, uint32_t x1,
                                              uint32_t* o0, uint32_t* o1) {
  const uint32_t ks0 = k0, ks1 = k1, ks2 = k0 ^ k1 ^ 0x1BD11BDAu;
  uint32_t v0 = x0 + ks0, v1 = x1 + ks1;
#define TF_ROUND(R) { v0 += v1; v1 = rotl32(v1, R); v1 ^= v0; }
  TF_ROUND(13) TF_ROUND(15) TF_ROUND(26) TF_ROUND(6)
  v0 += ks1; v1 += ks2 + 1u;
  TF_ROUND(17) TF_ROUND(29) TF_ROUND(16) TF_ROUND(24)
  v0 += ks2; v1 += ks0 + 2u;
  TF_ROUND(13) TF_ROUND(15) TF_ROUND(26) TF_ROUND(6)
  v0 += ks0; v1 += ks1 + 3u;
  TF_ROUND(17) TF_ROUND(29) TF_ROUND(16) TF_ROUND(24)
  v0 += ks1; v1 += ks2 + 4u;
  TF_ROUND(13) TF_ROUND(15) TF_ROUND(26) TF_ROUND(6)
  v0 += ks2; v1 += ks0 + 5u;
#undef TF_ROUND
  *o0 = v0; *o1 = v1;
}

// Partitionable random_bits (32-bit): bits[i] = y0 ^ y1 of hash(key,(0,i)).
__global__ void genbits_kernel(unsigned long long* __restrict__ keyarr,
                               uint32_t k0, uint32_t k1) {
  int i = blockIdx.x * 256 + threadIdx.x;
  uint32_t y0, y1;
  tf2x32(k0, k1, 0u, (uint32_t)i, &y0, &y1);
  uint32_t bits = y0 ^ y1;
  keyarr[i] = ((unsigned long long)bits << 32) | (uint32_t)i;
}

// ---- Bitonic sort, identical comparison network, split across launches ----
__global__ void bitonic_global_step(unsigned long long* __restrict__ d,
                                    int k, int j) {
  int t = blockIdx.x * 256 + threadIdx.x;   // 0..32767
  int low = t & (j - 1);
  int i   = ((t ^ low) << 1) | low;
  int ixj = i | j;
  bool up = ((i & k) == 0);
  unsigned long long a = d[i], b = d[ixj];
  if ((a > b) == up) { d[i] = b; d[ixj] = a; }
}

__global__ void bitonic_local_start(unsigned long long* __restrict__ d) {
  __shared__ unsigned long long s[2048];
  const int base = blockIdx.x * 2048;
  for (int u = threadIdx.x; u < 2048; u += 1024) s[u] = d[base + u];
  __syncthreads();
  for (int k = 2; k <= 2048; k <<= 1) {
    for (int j = k >> 1; j > 0; j >>= 1) {
      int t = threadIdx.x;
      int low = t & (j - 1);
      int il  = ((t ^ low) << 1) | low;
      int ixj = il | j;
      bool up = (((base + il) & k) == 0);
      unsigned long long a = s[il], b = s[ixj];
      if ((a > b) == up) { s[il] = b; s[ixj] = a; }
      __syncthreads();
    }
  }
  for (int u = threadIdx.x; u < 2048; u += 1024) d[base + u] = s[u];
}

__global__ void bitonic_local(unsigned long long* __restrict__ d, int k) {
  __shared__ unsigned long long s[2048];
  const int base = blockIdx.x * 2048;
  for (int u = threadIdx.x; u < 2048; u += 1024) s[u] = d[base + u];
  __syncthreads();
  for (int j = 1024; j > 0; j >>= 1) {
    int t = threadIdx.x;
    int low = t & (j - 1);
    int il  = ((t ^ low) << 1) | low;
    int ixj = il | j;
    bool up = (((base + il) & k) == 0);
    unsigned long long a = s[il], b = s[ixj];
    if ((a > b) == up) { s[il] = b; s[ixj] = a; }
    __syncthreads();
  }
  for (int u = threadIdx.x; u < 2048; u += 1024) d[base + u] = s[u];
}

__global__ void extract_low_kernel(const unsigned long long* __restrict__ s,
                                   uint32_t* __restrict__ out) {
  int i = blockIdx.x * 256 + threadIdx.x;
  out[i] = (uint32_t)(s[i] & 0xffffffffULL);
}

__global__ void init_centers_kernel(const unsigned long long* __restrict__ sorted2,
                                    const uint32_t* __restrict__ perm1,
                                    const float* __restrict__ x,
                                    float* __restrict__ ctr) {
  int k = blockIdx.x, d = threadIdx.x;
  uint32_t p   = (uint32_t)(sorted2[k] & 0xffffffffULL);
  uint32_t src = perm1[p];
  ctr[k * DIM + d] = x[(size_t)src * DIM + d];
}

// ---------------- bf16 2-way split helpers ----------------
__device__ static inline ushort f2bf(float f) {
  __hip_bfloat16 b = __float2bfloat16(f);
  return *reinterpret_cast<ushort*>(&b);
}
__device__ static inline float bf2f(ushort u) {
  __hip_bfloat16 b = *reinterpret_cast<__hip_bfloat16*>(&u);
  return __bfloat162float(b);
}
__device__ static inline void split2(float v, ushort& h, ushort& m) {
#pragma clang fp contract(off)
  h = f2bf(v);
  float r1 = v - bf2f(h);
  m = f2bf(r1);
}

// ---------------- per-iteration prep (fused cnorm + csplit + zero) --------
__global__ void prep_kernel(const float* __restrict__ ctr,
                            float* __restrict__ cnorm,
                            int* __restrict__ ambigCount,
                            ushort* __restrict__ ch,
                            ushort* __restrict__ cm) {
  __shared__ float row[DIM];
  const int k = blockIdx.x, t = threadIdx.x;
  if (k == 0 && t == 0) *ambigCount = 0;
  row[t]       = ctr[(size_t)k * DIM + t];
  row[t + 256] = ctr[(size_t)k * DIM + t + 256];
  __syncthreads();
#pragma unroll
  for (int u = t; u < DIM; u += 256) {
    ushort h, m;
    split2(row[u], h, m);
    ch[(size_t)k * DIM + u] = h;
    cm[(size_t)k * DIM + u] = m;
  }
  if (t == 0) {
#pragma clang fp contract(off)
    float s = 0.f;
    for (int j = 0; j < DIM; j++) {
      float v = row[j];
      float p = v * v;
      s = s + p;
    }
    cnorm[k] = s;
  }
}

// argmin fold: NaN is minimal; first index wins ties (lexicographic).
__device__ static inline void argmin_pick(float ov, int ok, float& bv, int& bk) {
  bool no = __builtin_isnan(ov), nb = __builtin_isnan(bv);
  bool take;
  if (no != nb)      take = no;
  else if (no)       take = ok < bk;
  else               take = (ov < bv) || (ov == bv && ok < bk);
  if (take) { bv = ov; bk = ok; }
}

// ---- (best, idx, second) triple machinery for margin tracking ----
__device__ static inline bool before3(float a, int ai, float b, int bi) {
  bool na = __builtin_isnan(a), nb = __builtin_isnan(b);
  if (na != nb) return na;
  if (na)       return ai < bi;
  return a < b || (a == b && ai < bi);
}
__device__ static inline float valmin3(float a, float b) {
  if (__builtin_isnan(a) || __builtin_isnan(b)) return __int_as_float(0x7fc00000);
  return fminf(a, b);
}
__device__ static inline void merge3(float ob, int oi, float os,
                                     float& b, int& i, float& s) {
  if (before3(ob, oi, b, i)) { s = valmin3(b, os); b = ob; i = oi; }
  else                        s = valmin3(s, ob);
}

// MFMA distance-GEMM + argmin + margin gate.  r15 geometry + DOUBLE-BUFFERED
// reg-staged A: issue next tile's global loads before compute, split+ds_write
// after, ONE barrier per k-step.  Element-identical staging and MFMA order
// -> bit-identical results to r15.
__launch_bounds__(256, 4)
__global__ void assign_mfma_kernel(const float* __restrict__ x,
                                   const ushort* __restrict__ ch,
                                   const ushort* __restrict__ cm,
                                   const float* __restrict__ cnorm,
                                   int* __restrict__ assign,
                                   int* __restrict__ ambigCount,
                                   int* __restrict__ ambigList) {
  __shared__ __align__(16) ushort ah[2][64][40], am[2][64][40];   // 20.5 KB
  __shared__ float  redv[4][64];
  __shared__ int    redi[4][64];
  __shared__ float  reds[4][64];

  const int t = threadIdx.x;
  const int w = t >> 6;
  const int lane = t & 63;
  const int m0 = blockIdx.x * BM;
  const int colbase = w * 64;
  const int l15 = lane & 15, l4 = lane >> 4;
  const int sr = t >> 2, sko = (t & 3) * 8;        // staging map (as r15)
  const float* srcbase = &x[(size_t)(m0 + sr) * DIM + sko];

  f32x4 acc[4][4];
#pragma unroll
  for (int i = 0; i < 4; i++)
#pragma unroll
    for (int j = 0; j < 4; j++) acc[i][j] = (f32x4)(0.f);

  // prologue: stage k0=0 into buf 0
  {
    float4 v0 = *reinterpret_cast<const float4*>(srcbase);
    float4 v1 = *reinterpret_cast<const float4*>(srcbase + 4);
    float vv[8] = {v0.x, v0.y, v0.z, v0.w, v1.x, v1.y, v1.z, v1.w};
    bf16x8 vh, vm;
#pragma unroll
    for (int q = 0; q < 8; q++) {
      ushort h, m;
      split2(vv[q], h, m);
      vh[q] = (short)h; vm[q] = (short)m;
    }
    *reinterpret_cast<bf16x8*>(&ah[0][sr][sko]) = vh;
    *reinterpret_cast<bf16x8*>(&am[0][sr][sko]) = vm;
  }
  __syncthreads();

  int cur = 0;
  for (int ks = 0; ks < 16; ks++) {
    const int k0 = ks * 32;
    const bool pf = (ks + 1 < 16);
    float4 v0, v1;
    if (pf) {                                 // issue next-tile loads early
      v0 = *reinterpret_cast<const float4*>(srcbase + k0 + 32);
      v1 = *reinterpret_cast<const float4*>(srcbase + k0 + 36);
    }
    bf16x8 bh[4], bm_[4];
    {
      size_t rowoff = (size_t)(colbase + l15) * DIM + k0 + l4 * 8;
#pragma unroll
      for (int j = 0; j < 4; j++) {
        size_t off = rowoff + (size_t)j * 16 * DIM;
        bh[j]  = *reinterpret_cast<const bf16x8*>(&ch[off]);
        bm_[j] = *reinterpret_cast<const bf16x8*>(&cm[off]);
      }
    }
#pragma unroll
    for (int i = 0; i < 4; i++) {
      int r = i * 16 + l15, ko = l4 * 8;
      bf16x8 fah = *reinterpret_cast<bf16x8*>(&ah[cur][r][ko]);
      bf16x8 fam = *reinterpret_cast<bf16x8*>(&am[cur][r][ko]);
#pragma unroll
      for (int j = 0; j < 4; j++) {
        acc[i][j] = __builtin_amdgcn_mfma_f32_16x16x32_bf16(fah, bh[j],  acc[i][j], 0, 0, 0);
        acc[i][j] = __builtin_amdgcn_mfma_f32_16x16x32_bf16(fah, bm_[j], acc[i][j], 0, 0, 0);
        acc[i][j] = __builtin_amdgcn_mfma_f32_16x16x32_bf16(fam, bh[j],  acc[i][j], 0, 0, 0);
      }
    }
    if (pf) {                                 // split + write into other buf
      float vv[8] = {v0.x, v0.y, v0.z, v0.w, v1.x, v1.y, v1.z, v1.w};
      bf16x8 vh, vm;
#pragma unroll
      for (int q = 0; q < 8; q++) {
        ushort h, m;
        split2(vv[q], h, m);
        vh[q] = (short)h; vm[q] = (short)m;
      }
      *reinterpret_cast<bf16x8*>(&ah[cur ^ 1][sr][sko]) = vh;
      *reinterpret_cast<bf16x8*>(&am[cur ^ 1][sr][sko]) = vm;
    }
    __syncthreads();
    cur ^= 1;
  }

  // ---- epilogue: d2 = cnorm - 2*dot; (best, idx, second); margin gate ----
  {
#pragma clang fp contract(off)
    float cn[4];
#pragma unroll
    for (int j = 0; j < 4; j++) cn[j] = cnorm[colbase + j * 16 + l15];

#pragma unroll
    for (int i = 0; i < 4; i++) {
#pragma unroll
      for (int reg = 0; reg < 4; reg++) {
        float bb = __int_as_float(0x7f800000);  // +inf
        int   bi = 0x7fffffff;
        float bs = __int_as_float(0x7f800000);
#pragma unroll
        for (int j = 0; j < 4; j++) {
          int col = colbase + j * 16 + l15;
          float d2 = cn[j] - 2.0f * acc[i][j][reg];
          merge3(d2, col, __int_as_float(0x7f800000), bb, bi, bs);
        }
#pragma unroll
        for (int s = 1; s < 16; s <<= 1) {
          float ob = __shfl_xor(bb, s);
          int   oi = __shfl_xor(bi, s);
          float os = __shfl_xor(bs, s);
          merge3(ob, oi, os, bb, bi, bs);
        }
        if (l15 == 0) {
          int row = i * 16 + l4 * 4 + reg;
          redv[w][row] = bb; redi[w][row] = bi; reds[w][row] = bs;
        }
      }
    }
    __syncthreads();
    if (t < 64) {
      float bb = __int_as_float(0x7f800000);
      int   bi = 0x7fffffff;
      float bs = __int_as_float(0x7f800000);
#pragma unroll
      for (int w2 = 0; w2 < 4; w2++)
        merge3(redv[w2][t], redi[w2][t], reds[w2][t], bb, bi, bs);
      assign[m0 + t] = bi;
      float margin = bs - bb;
      if (!(margin > TAU)) {                 // NaN margin also flags
        int pos = atomicAdd(ambigCount, 1);
        if (pos < N_PTS) ambigList[pos] = m0 + t;
      }
    }
  }
}

// Exact recheck of ambiguous points with the r5 bit-exact scheme.
__launch_bounds__(256)
__global__ void refine_kernel(const float* __restrict__ x,
                              const float* __restrict__ ctr,
                              const float* __restrict__ cnorm,
                              const int* __restrict__ ambigList,
                              const int* __restrict__ ambigCount,
                              int* __restrict__ assign) {
  __shared__ float xrow[DIM];
  __shared__ float cs[K_CL][33];
  __shared__ float rv[K_CL];
  __shared__ int   ri[K_CL];
  const int t = threadIdx.x;
  int cnt = *ambigCount; if (cnt > N_PTS) cnt = N_PTS;
  for (int a = blockIdx.x; a < cnt; a += gridDim.x) {
    int pt = ambigList[a];
    __syncthreads();
    for (int u = t; u < DIM; u += 256) xrow[u] = x[(size_t)pt * DIM + u];
    float accA = 0.f, accB = 0.f;
    for (int c = 0; c < 16; c++) {
      __syncthreads();
      for (int u = t; u < K_CL * 32; u += 256) {
        int k = u >> 5, j = u & 31;
        cs[k][j] = ctr[(size_t)k * DIM + c * 32 + j];
      }
      __syncthreads();
      {
#pragma clang fp contract(off)
        float s = (c < 9) ? accA : accB;
        for (int j = 0; j < 32; j++) {
          float pv = xrow[c * 32 + j] * cs[t][j];
          s = s + pv;
        }
        if (c < 9) accA = s; else accB = s;
      }
    }
    float d2;
    {
#pragma clang fp contract(off)
      float dot = accA + accB;
      float tw = 2.0f * dot;
      d2 = cnorm[t] - tw;
    }
    rv[t] = d2; ri[t] = t;
    __syncthreads();
    for (int st = 128; st >= 1; st >>= 1) {
      if (t < st) argmin_pick(rv[t + st], ri[t + st], rv[t], ri[t]);
      __syncthreads();
    }
    if (t == 0) assign[pt] = ri[0];
  }
}

// Counting sort stage 1: per-block histogram, BLOCK-major output (coalesced).
__global__ void hist_kernel(const int* __restrict__ assign, int* __restrict__ blockHist) {
  __shared__ int h[K_CL];
  int b = blockIdx.x, t = threadIdx.x;
  h[t] = 0; __syncthreads();
  int k = assign[b * 256 + t];
  atomicAdd(&h[k], 1);
  __syncthreads();
  blockHist[b * 256 + t] = h[t];
}

// Stage 2a: per-cluster exclusive scan over the 256 block values (parallel).
__global__ void scan_blocks_kernel(int* __restrict__ blockHist,
                                   int* __restrict__ counts) {
  __shared__ int v[256];
  int k = blockIdx.x, b = threadIdx.x;
  int x = blockHist[b * 256 + k];
  v[b] = x;
  __syncthreads();
  for (int s = 1; s < 256; s <<= 1) {
    int add = (b >= s) ? v[b - s] : 0;
    __syncthreads();
    v[b] += add;
    __syncthreads();
  }
  blockHist[b * 256 + k] = v[b] - x;
  if (b == 255) counts[k] = v[255];
}

// Stage 2b: exclusive scan of cluster totals -> clusterStart. One block.
__global__ void scan_clusters_kernel(const int* __restrict__ counts,
                                     int* __restrict__ clusterStart) {
  __shared__ int v[256];
  int k = threadIdx.x;
  int x = counts[k];
  v[k] = x;
  __syncthreads();
  for (int s = 1; s < 256; s <<= 1) {
    int add = (k >= s) ? v[k - s] : 0;
    __syncthreads();
    v[k] += add;
    __syncthreads();
  }
  clusterStart[k] = v[k] - x;
}

// Stage 3: stable scatter of point indices into cluster-sorted order.
__global__ void scatter_kernel(const int* __restrict__ assign,
                               const int* __restrict__ blockHist,
                               const int* __restrict__ clusterStart,
                               int* __restrict__ sortedIdx) {
  __shared__ int la[256];
  int b = blockIdx.x, t = threadIdx.x;
  int n = b * 256 + t;
  int k = assign[n];
  la[t] = k; __syncthreads();
  int rank = 0;
  for (int u = 0; u < t; u++) rank += (la[u] == k) ? 1 : 0;
  sortedIdx[clusterStart[k] + blockHist[b * 256 + k] + rank] = n;
}

// Stage 4a: per-(cluster, chunk) partial sums, nch chunks per cluster.
__global__ void segsum_part_kernel(const float* __restrict__ x,
                                   const int* __restrict__ sortedIdx,
                                   const int* __restrict__ clusterStart,
                                   const int* __restrict__ counts,
                                   float* __restrict__ part, int nch) {
#pragma clang fp contract(off)
  int k = blockIdx.x / nch;      // cluster
  int c = blockIdx.x - k * nch;  // chunk
  int d = threadIdx.x;
  int start = clusterStart[k], cnt = counts[k];
  int ch = (cnt + nch - 1) / nch;
  int b0 = c * ch;
  int b1 = b0 + ch; if (b1 > cnt) b1 = cnt;
  float s = 0.f;
  for (int i = b0; i < b1; i++) {
    int idx = sortedIdx[start + i];
    s = s + x[(size_t)idx * DIM + d];
  }
  part[((size_t)k * nch + c) * DIM + d] = s;
}

// Stage 4b: combine chunks in fixed ascending order, divide.
__global__ void segsum_final_kernel(const float* __restrict__ part,
                                    const int* __restrict__ counts,
                                    float* __restrict__ out, int nch) {
#pragma clang fp contract(off)
  int k = blockIdx.x, d = threadIdx.x;
  float s = 0.f;
  for (int c = 0; c < nch; c++)
    s = s + part[((size_t)k * nch + c) * DIM + d];
  out[k * DIM + d] = s / (float)counts[k];   // cnt==0 -> NaN, matches ref
}

// ---------------- host ----------------
static inline void run_sort(unsigned long long* d, hipStream_t stream) {
  bitonic_local_start<<<32, 1024, 0, stream>>>(d);
  for (int k = 4096; k <= 65536; k <<= 1) {
    for (int j = k >> 1; j >= 2048; j >>= 1)
      bitonic_global_step<<<128, 256, 0, stream>>>(d, k, j);
    bitonic_local<<<32, 1024, 0, stream>>>(d, k);
  }
}

extern "C" void kernel_launch(void* const* d_in, const int* in_sizes, int n_in,
                              void* d_out, int out_size, void* d_ws, size_t ws_size,
                              hipStream_t stream) {
  const float* x = (const float*)d_in[0];
  float* out = (float*)d_out;

  char* p = (char*)d_ws;
  size_t used = 0;
  auto alloc = [&](size_t bytes) {
    char* r = p;
    size_t rb = (bytes + 255) & ~(size_t)255;
    p += rb; used += rb;
    return r;
  };
  unsigned long long* keyA = (unsigned long long*)alloc(N_PTS * 8);
  unsigned long long* keyB = (unsigned long long*)alloc(N_PTS * 8);
  uint32_t* perm1          = (uint32_t*)alloc(N_PTS * 4);
  int* assign              = (int*)alloc(N_PTS * 4);
  int* blockHist           = (int*)alloc(K_CL * 256 * 4);
  int* clusterStart        = (int*)alloc(K_CL * 4);
  int* counts              = (int*)alloc(K_CL * 4);
  int* sortedIdx           = (int*)alloc(N_PTS * 4);
  float* ctrA              = (float*)alloc(K_CL * DIM * 4);
  float* ctrB              = (float*)alloc(K_CL * DIM * 4);
  float* cnorm             = (float*)alloc(K_CL * 4);
  ushort* ch               = (ushort*)alloc((size_t)K_CL * DIM * 2);
  ushort* cm               = (ushort*)alloc((size_t)K_CL * DIM * 2);
  int* ambigCount          = (int*)alloc(4);
  int* ambigList           = (int*)alloc(N_PTS * 4);

  // Chunk count for segsum: 64 if workspace allows, else 8.
  const size_t part64 = (size_t)K_CL * 64 * DIM * 4;   // 33.5 MB
  int nch = (ws_size >= used + part64 + 256) ? 64 : 8;
  float* part = (float*)alloc((size_t)K_CL * nch * DIM * 4);

  // Partitionable (foldlike) threefry split: split(key)[j] = hash(key,(0,j)).
  uint32_t k1a, k1b, s1a, s1b;
  tf2x32(0u, 1u, 0u, 0u, &k1a, &k1b);
  tf2x32(0u, 1u, 0u, 1u, &s1a, &s1b);
  uint32_t k2a, k2b, s2a, s2b;
  tf2x32(k1a, k1b, 0u, 0u, &k2a, &k2b);
  tf2x32(k1a, k1b, 0u, 1u, &s2a, &s2b);

  genbits_kernel<<<256, 256, 0, stream>>>(keyA, s1a, s1b);
  run_sort(keyA, stream);
  extract_low_kernel<<<256, 256, 0, stream>>>(keyA, perm1);
  genbits_kernel<<<256, 256, 0, stream>>>(keyB, s2a, s2b);
  run_sort(keyB, stream);
  init_centers_kernel<<<K_CL, DIM, 0, stream>>>(keyB, perm1, x, ctrA);

  float* cur = ctrA;
  for (int it = 0; it < ITERS; ++it) {
    float* next = (it == ITERS - 1) ? out : ((it & 1) ? ctrA : ctrB);
    prep_kernel<<<K_CL, 256, 0, stream>>>(cur, cnorm, ambigCount, ch, cm);
    assign_mfma_kernel<<<N_PTS / BM, 256, 0, stream>>>(x, ch, cm, cnorm, assign,
                                                       ambigCount, ambigList);
    refine_kernel<<<1024, 256, 0, stream>>>(x, cur, cnorm, ambigList, ambigCount, assign);
    hist_kernel<<<256, 256, 0, stream>>>(assign, blockHist);
    scan_blocks_kernel<<<256, 256, 0, stream>>>(blockHist, counts);
    scan_clusters_kernel<<<1, 256, 0, stream>>>(counts, clusterStart);
    scatter_kernel<<<256, 256, 0, stream>>>(assign, blockHist, clusterStart, sortedIdx);
    segsum_part_kernel<<<K_CL * nch, DIM, 0, stream>>>(x, sortedIdx, clusterStart,
                                                       counts, part, nch);
    segsum_final_kernel<<<K_CL, DIM, 0, stream>>>(part, counts, next, nch);
    cur = next;
  }
}

// Round 18
// 6653.015 us; speedup vs baseline: 1.0855x; 1.0098x over previous
//
#include <hip/hip_runtime.h>
#include <hip/hip_bf16.h>
#include <stdint.h>

#define N_PTS   65536
#define DIM     512
#define K_CL    256
#define ITERS   25
#define BM      64         // points per block in assign
#define TAU     1e-2f      // ambiguity margin; fast-path err max ~1e-3 << TAU/2

typedef __attribute__((ext_vector_type(8))) short  bf16x8;   // 8 bf16 (4 VGPRs)
typedef __attribute__((ext_vector_type(4))) float  f32x4;

// ---------------- Threefry-2x32 (JAX-exact, 20 rounds) ----------------
__host__ __device__ static inline uint32_t rotl32(uint32_t x, int d) {
  return (x << d) | (x >> (32 - d));
}

__host__ __device__ static inline void tf2x32(uint32_t k0, uint32_t k1,
                                              uint32_t x0, uint32_t x1,
                                              uint32_t* o0, uint32_t* o1) {
  const uint32_t ks0 = k0, ks1 = k1, ks2 = k0 ^ k1 ^ 0x1BD11BDAu;
  uint32_t v0 = x0 + ks0, v1 = x1 + ks1;
#define TF_ROUND(R) { v0 += v1; v1 = rotl32(v1, R); v1 ^= v0; }
  TF_ROUND(13) TF_ROUND(15) TF_ROUND(26) TF_ROUND(6)
  v0 += ks1; v1 += ks2 + 1u;
  TF_ROUND(17) TF_ROUND(29) TF_ROUND(16) TF_ROUND(24)
  v0 += ks2; v1 += ks0 + 2u;
  TF_ROUND(13) TF_ROUND(15) TF_ROUND(26) TF_ROUND(6)
  v0 += ks0; v1 += ks1 + 3u;
  TF_ROUND(17) TF_ROUND(29) TF_ROUND(16) TF_ROUND(24)
  v0 += ks1; v1 += ks2 + 4u;
  TF_ROUND(13) TF_ROUND(15) TF_ROUND(26) TF_ROUND(6)
  v0 += ks2; v1 += ks0 + 5u;
#undef TF_ROUND
  *o0 = v0; *o1 = v1;
}

// Partitionable random_bits (32-bit): bits[i] = y0 ^ y1 of hash(key,(0,i)).
__global__ void genbits_kernel(unsigned long long* __restrict__ keyarr,
                               uint32_t k0, uint32_t k1) {
  int i = blockIdx.x * 256 + threadIdx.x;
  uint32_t y0, y1;
  tf2x32(k0, k1, 0u, (uint32_t)i, &y0, &y1);
  uint32_t bits = y0 ^ y1;
  keyarr[i] = ((unsigned long long)bits << 32) | (uint32_t)i;
}

// ---- Bitonic sort, identical comparison network, split across launches ----
__global__ void bitonic_global_step(unsigned long long* __restrict__ d,
                                    int k, int j) {
  int t = blockIdx.x * 256 + threadIdx.x;   // 0..32767
  int low = t & (j - 1);
  int i   = ((t ^ low) << 1) | low;
  int ixj = i | j;
  bool up = ((i & k) == 0);
  unsigned long long a = d[i], b = d[ixj];
  if ((a > b) == up) { d[i] = b; d[ixj] = a; }
}

__global__ void bitonic_local_start(unsigned long long* __restrict__ d) {
  __shared__ unsigned long long s[2048];
  const int base = blockIdx.x * 2048;
  for (int u = threadIdx.x; u < 2048; u += 1024) s[u] = d[base + u];
  __syncthreads();
  for (int k = 2; k <= 2048; k <<= 1) {
    for (int j = k >> 1; j > 0; j >>= 1) {
      int t = threadIdx.x;
      int low = t & (j - 1);
      int il  = ((t ^ low) << 1) | low;
      int ixj = il | j;
      bool up = (((base + il) & k) == 0);
      unsigned long long a = s[il], b = s[ixj];
      if ((a > b) == up) { s[il] = b; s[ixj] = a; }
      __syncthreads();
    }
  }
  for (int u = threadIdx.x; u < 2048; u += 1024) d[base + u] = s[u];
}

__global__ void bitonic_local(unsigned long long* __restrict__ d, int k) {
  __shared__ unsigned long long s[2048];
  const int base = blockIdx.x * 2048;
  for (int u = threadIdx.x; u < 2048; u += 1024) s[u] = d[base + u];
  __syncthreads();
  for (int j = 1024; j > 0; j >>= 1) {
    int t = threadIdx.x;
    int low = t & (j - 1);
    int il  = ((t ^ low) << 1) | low;
    int ixj = il | j;
    bool up = (((base + il) & k) == 0);
    unsigned long long a = s[il], b = s[ixj];
    if ((a > b) == up) { s[il] = b; s[ixj] = a; }
    __syncthreads();
  }
  for (int u = threadIdx.x; u < 2048; u += 1024) d[base + u] = s[u];
}

__global__ void extract_low_kernel(const unsigned long long* __restrict__ s,
                                   uint32_t* __restrict__ out) {
  int i = blockIdx.x * 256 + threadIdx.x;
  out[i] = (uint32_t)(s[i] & 0xffffffffULL);
}

__global__ void init_centers_kernel(const unsigned long long* __restrict__ sorted2,
                                    const uint32_t* __restrict__ perm1,
                                    const float* __restrict__ x,
                                    float* __restrict__ ctr) {
  int k = blockIdx.x, d = threadIdx.x;
  uint32_t p   = (uint32_t)(sorted2[k] & 0xffffffffULL);
  uint32_t src = perm1[p];
  ctr[k * DIM + d] = x[(size_t)src * DIM + d];
}

// ---------------- bf16 2-way split helpers ----------------
__device__ static inline ushort f2bf(float f) {
  __hip_bfloat16 b = __float2bfloat16(f);
  return *reinterpret_cast<ushort*>(&b);
}
__device__ static inline float bf2f(ushort u) {
  __hip_bfloat16 b = *reinterpret_cast<__hip_bfloat16*>(&u);
  return __bfloat162float(b);
}
__device__ static inline void split2(float v, ushort& h, ushort& m) {
#pragma clang fp contract(off)
  h = f2bf(v);
  float r1 = v - bf2f(h);
  m = f2bf(r1);
}

// ---------------- iteration-0 prep (cnorm + csplit + zero) ----------------
__global__ void prep_kernel(const float* __restrict__ ctr,
                            float* __restrict__ cnorm,
                            int* __restrict__ ambigCount,
                            ushort* __restrict__ ch,
                            ushort* __restrict__ cm) {
  __shared__ float row[DIM];
  const int k = blockIdx.x, t = threadIdx.x;
  if (k == 0 && t == 0) *ambigCount = 0;
  row[t]       = ctr[(size_t)k * DIM + t];
  row[t + 256] = ctr[(size_t)k * DIM + t + 256];
  __syncthreads();
#pragma unroll
  for (int u = t; u < DIM; u += 256) {
    ushort h, m;
    split2(row[u], h, m);
    ch[(size_t)k * DIM + u] = h;
    cm[(size_t)k * DIM + u] = m;
  }
  if (t == 0) {
#pragma clang fp contract(off)
    float s = 0.f;
    for (int j = 0; j < DIM; j++) {
      float v = row[j];
      float p = v * v;
      s = s + p;
    }
    cnorm[k] = s;
  }
}

// argmin fold: NaN is minimal; first index wins ties (lexicographic).
__device__ static inline void argmin_pick(float ov, int ok, float& bv, int& bk) {
  bool no = __builtin_isnan(ov), nb = __builtin_isnan(bv);
  bool take;
  if (no != nb)      take = no;
  else if (no)       take = ok < bk;
  else               take = (ov < bv) || (ov == bv && ok < bk);
  if (take) { bv = ov; bk = ok; }
}

// ---- (best, idx, second) triple machinery for margin tracking ----
__device__ static inline bool before3(float a, int ai, float b, int bi) {
  bool na = __builtin_isnan(a), nb = __builtin_isnan(b);
  if (na != nb) return na;
  if (na)       return ai < bi;
  return a < b || (a == b && ai < bi);
}
__device__ static inline float valmin3(float a, float b) {
  if (__builtin_isnan(a) || __builtin_isnan(b)) return __int_as_float(0x7fc00000);
  return fminf(a, b);
}
__device__ static inline void merge3(float ob, int oi, float os,
                                     float& b, int& i, float& s) {
  if (before3(ob, oi, b, i)) { s = valmin3(b, os); b = ob; i = oi; }
  else                        s = valmin3(s, ob);
}

// MFMA distance-GEMM + argmin + margin gate (r17 proven, frozen):
// double-buffered reg-staged A, one barrier per k-step, 2-way split,
// 3 products (hH, hM, mH).
__launch_bounds__(256, 4)
__global__ void assign_mfma_kernel(const float* __restrict__ x,
                                   const ushort* __restrict__ ch,
                                   const ushort* __restrict__ cm,
                                   const float* __restrict__ cnorm,
                                   int* __restrict__ assign,
                                   int* __restrict__ ambigCount,
                                   int* __restrict__ ambigList) {
  __shared__ __align__(16) ushort ah[2][64][40], am[2][64][40];   // 20.5 KB
  __shared__ float  redv[4][64];
  __shared__ int    redi[4][64];
  __shared__ float  reds[4][64];

  const int t = threadIdx.x;
  const int w = t >> 6;
  const int lane = t & 63;
  const int m0 = blockIdx.x * BM;
  const int colbase = w * 64;
  const int l15 = lane & 15, l4 = lane >> 4;
  const int sr = t >> 2, sko = (t & 3) * 8;        // staging map
  const float* srcbase = &x[(size_t)(m0 + sr) * DIM + sko];

  f32x4 acc[4][4];
#pragma unroll
  for (int i = 0; i < 4; i++)
#pragma unroll
    for (int j = 0; j < 4; j++) acc[i][j] = (f32x4)(0.f);

  // prologue: stage k0=0 into buf 0
  {
    float4 v0 = *reinterpret_cast<const float4*>(srcbase);
    float4 v1 = *reinterpret_cast<const float4*>(srcbase + 4);
    float vv[8] = {v0.x, v0.y, v0.z, v0.w, v1.x, v1.y, v1.z, v1.w};
    bf16x8 vh, vm;
#pragma unroll
    for (int q = 0; q < 8; q++) {
      ushort h, m;
      split2(vv[q], h, m);
      vh[q] = (short)h; vm[q] = (short)m;
    }
    *reinterpret_cast<bf16x8*>(&ah[0][sr][sko]) = vh;
    *reinterpret_cast<bf16x8*>(&am[0][sr][sko]) = vm;
  }
  __syncthreads();

  int cur = 0;
  for (int ks = 0; ks < 16; ks++) {
    const int k0 = ks * 32;
    const bool pf = (ks + 1 < 16);
    float4 v0, v1;
    if (pf) {                                 // issue next-tile loads early
      v0 = *reinterpret_cast<const float4*>(srcbase + k0 + 32);
      v1 = *reinterpret_cast<const float4*>(srcbase + k0 + 36);
    }
    bf16x8 bh[4], bm_[4];
    {
      size_t rowoff = (size_t)(colbase + l15) * DIM + k0 + l4 * 8;
#pragma unroll
      for (int j = 0; j < 4; j++) {
        size_t off = rowoff + (size_t)j * 16 * DIM;
        bh[j]  = *reinterpret_cast<const bf16x8*>(&ch[off]);
        bm_[j] = *reinterpret_cast<const bf16x8*>(&cm[off]);
      }
    }
#pragma unroll
    for (int i = 0; i < 4; i++) {
      int r = i * 16 + l15, ko = l4 * 8;
      bf16x8 fah = *reinterpret_cast<bf16x8*>(&ah[cur][r][ko]);
      bf16x8 fam = *reinterpret_cast<bf16x8*>(&am[cur][r][ko]);
#pragma unroll
      for (int j = 0; j < 4; j++) {
        acc[i][j] = __builtin_amdgcn_mfma_f32_16x16x32_bf16(fah, bh[j],  acc[i][j], 0, 0, 0);
        acc[i][j] = __builtin_amdgcn_mfma_f32_16x16x32_bf16(fah, bm_[j], acc[i][j], 0, 0, 0);
        acc[i][j] = __builtin_amdgcn_mfma_f32_16x16x32_bf16(fam, bh[j],  acc[i][j], 0, 0, 0);
      }
    }
    if (pf) {                                 // split + write into other buf
      float vv[8] = {v0.x, v0.y, v0.z, v0.w, v1.x, v1.y, v1.z, v1.w};
      bf16x8 vh, vm;
#pragma unroll
      for (int q = 0; q < 8; q++) {
        ushort h, m;
        split2(vv[q], h, m);
        vh[q] = (short)h; vm[q] = (short)m;
      }
      *reinterpret_cast<bf16x8*>(&ah[cur ^ 1][sr][sko]) = vh;
      *reinterpret_cast<bf16x8*>(&am[cur ^ 1][sr][sko]) = vm;
    }
    __syncthreads();
    cur ^= 1;
  }

  // ---- epilogue: d2 = cnorm - 2*dot; (best, idx, second); margin gate ----
  {
#pragma clang fp contract(off)
    float cn[4];
#pragma unroll
    for (int j = 0; j < 4; j++) cn[j] = cnorm[colbase + j * 16 + l15];

#pragma unroll
    for (int i = 0; i < 4; i++) {
#pragma unroll
      for (int reg = 0; reg < 4; reg++) {
        float bb = __int_as_float(0x7f800000);  // +inf
        int   bi = 0x7fffffff;
        float bs = __int_as_float(0x7f800000);
#pragma unroll
        for (int j = 0; j < 4; j++) {
          int col = colbase + j * 16 + l15;
          float d2 = cn[j] - 2.0f * acc[i][j][reg];
          merge3(d2, col, __int_as_float(0x7f800000), bb, bi, bs);
        }
#pragma unroll
        for (int s = 1; s < 16; s <<= 1) {
          float ob = __shfl_xor(bb, s);
          int   oi = __shfl_xor(bi, s);
          float os = __shfl_xor(bs, s);
          merge3(ob, oi, os, bb, bi, bs);
        }
        if (l15 == 0) {
          int row = i * 16 + l4 * 4 + reg;
          redv[w][row] = bb; redi[w][row] = bi; reds[w][row] = bs;
        }
      }
    }
    __syncthreads();
    if (t < 64) {
      float bb = __int_as_float(0x7f800000);
      int   bi = 0x7fffffff;
      float bs = __int_as_float(0x7f800000);
#pragma unroll
      for (int w2 = 0; w2 < 4; w2++)
        merge3(redv[w2][t], redi[w2][t], reds[w2][t], bb, bi, bs);
      assign[m0 + t] = bi;
      float margin = bs - bb;
      if (!(margin > TAU)) {                 // NaN margin also flags
        int pos = atomicAdd(ambigCount, 1);
        if (pos < N_PTS) ambigList[pos] = m0 + t;
      }
    }
  }
}

// Exact recheck of ambiguous points with the r5 bit-exact scheme.
__launch_bounds__(256)
__global__ void refine_kernel(const float* __restrict__ x,
                              const float* __restrict__ ctr,
                              const float* __restrict__ cnorm,
                              const int* __restrict__ ambigList,
                              const int* __restrict__ ambigCount,
                              int* __restrict__ assign) {
  __shared__ float xrow[DIM];
  __shared__ float cs[K_CL][33];
  __shared__ float rv[K_CL];
  __shared__ int   ri[K_CL];
  const int t = threadIdx.x;
  int cnt = *ambigCount; if (cnt > N_PTS) cnt = N_PTS;
  for (int a = blockIdx.x; a < cnt; a += gridDim.x) {
    int pt = ambigList[a];
    __syncthreads();
    for (int u = t; u < DIM; u += 256) xrow[u] = x[(size_t)pt * DIM + u];
    float accA = 0.f, accB = 0.f;
    for (int c = 0; c < 16; c++) {
      __syncthreads();
      for (int u = t; u < K_CL * 32; u += 256) {
        int k = u >> 5, j = u & 31;
        cs[k][j] = ctr[(size_t)k * DIM + c * 32 + j];
      }
      __syncthreads();
      {
#pragma clang fp contract(off)
        float s = (c < 9) ? accA : accB;
        for (int j = 0; j < 32; j++) {
          float pv = xrow[c * 32 + j] * cs[t][j];
          s = s + pv;
        }
        if (c < 9) accA = s; else accB = s;
      }
    }
    float d2;
    {
#pragma clang fp contract(off)
      float dot = accA + accB;
      float tw = 2.0f * dot;
      d2 = cnorm[t] - tw;
    }
    rv[t] = d2; ri[t] = t;
    __syncthreads();
    for (int st = 128; st >= 1; st >>= 1) {
      if (t < st) argmin_pick(rv[t + st], ri[t + st], rv[t], ri[t]);
      __syncthreads();
    }
    if (t == 0) assign[pt] = ri[0];
  }
}

// Counting sort stage 1: per-block histogram, BLOCK-major output (coalesced).
__global__ void hist_kernel(const int* __restrict__ assign, int* __restrict__ blockHist) {
  __shared__ int h[K_CL];
  int b = blockIdx.x, t = threadIdx.x;
  h[t] = 0; __syncthreads();
  int k = assign[b * 256 + t];
  atomicAdd(&h[k], 1);
  __syncthreads();
  blockHist[b * 256 + t] = h[t];
}

// Stage 2a: per-cluster exclusive scan over the 256 block values (parallel).
__global__ void scan_blocks_kernel(int* __restrict__ blockHist,
                                   int* __restrict__ counts) {
  __shared__ int v[256];
  int k = blockIdx.x, b = threadIdx.x;
  int x = blockHist[b * 256 + k];
  v[b] = x;
  __syncthreads();
  for (int s = 1; s < 256; s <<= 1) {
    int add = (b >= s) ? v[b - s] : 0;
    __syncthreads();
    v[b] += add;
    __syncthreads();
  }
  blockHist[b * 256 + k] = v[b] - x;
  if (b == 255) counts[k] = v[255];
}

// Stage 2b: exclusive scan of cluster totals -> clusterStart. One block.
__global__ void scan_clusters_kernel(const int* __restrict__ counts,
                                     int* __restrict__ clusterStart) {
  __shared__ int v[256];
  int k = threadIdx.x;
  int x = counts[k];
  v[k] = x;
  __syncthreads();
  for (int s = 1; s < 256; s <<= 1) {
    int add = (k >= s) ? v[k - s] : 0;
    __syncthreads();
    v[k] += add;
    __syncthreads();
  }
  clusterStart[k] = v[k] - x;
}

// Stage 3: stable scatter of point indices into cluster-sorted order.
__global__ void scatter_kernel(const int* __restrict__ assign,
                               const int* __restrict__ blockHist,
                               const int* __restrict__ clusterStart,
                               int* __restrict__ sortedIdx) {
  __shared__ int la[256];
  int b = blockIdx.x, t = threadIdx.x;
  int n = b * 256 + t;
  int k = assign[n];
  la[t] = k; __syncthreads();
  int rank = 0;
  for (int u = 0; u < t; u++) rank += (la[u] == k) ? 1 : 0;
  sortedIdx[clusterStart[k] + blockHist[b * 256 + k] + rank] = n;
}

// Stage 4a: per-(cluster, chunk) partial sums, nch chunks per cluster.
__global__ void segsum_part_kernel(const float* __restrict__ x,
                                   const int* __restrict__ sortedIdx,
                                   const int* __restrict__ clusterStart,
                                   const int* __restrict__ counts,
                                   float* __restrict__ part, int nch) {
#pragma clang fp contract(off)
  int k = blockIdx.x / nch;      // cluster
  int c = blockIdx.x - k * nch;  // chunk
  int d = threadIdx.x;
  int start = clusterStart[k], cnt = counts[k];
  int ch = (cnt + nch - 1) / nch;
  int b0 = c * ch;
  int b1 = b0 + ch; if (b1 > cnt) b1 = cnt;
  float s = 0.f;
  for (int i = b0; i < b1; i++) {
    int idx = sortedIdx[start + i];
    s = s + x[(size_t)idx * DIM + d];
  }
  part[((size_t)k * nch + c) * DIM + d] = s;
}

// Stage 4b (last iter): combine chunks ascending, divide -> out.
__global__ void segsum_final_kernel(const float* __restrict__ part,
                                    const int* __restrict__ counts,
                                    float* __restrict__ out, int nch) {
#pragma clang fp contract(off)
  int k = blockIdx.x, d = threadIdx.x;
  float s = 0.f;
  for (int c = 0; c < nch; c++)
    s = s + part[((size_t)k * nch + c) * DIM + d];
  out[k * DIM + d] = s / (float)counts[k];   // cnt==0 -> NaN, matches ref
}

// Stage 4b + prep fused (iters 0..ITERS-2): combine chunks -> next centers
// (same ascending fold as segsum_final), split to bf16 planes, cnorm in the
// same strict-sequential order, zero ambigCount.  256 blocks x 512 threads.
// No atomics; counts is rewritten by scan_blocks each iteration.
__global__ void update_kernel(const float* __restrict__ part,
                              const int* __restrict__ counts,
                              float* __restrict__ ctrNext,
                              float* __restrict__ cnorm,
                              int* __restrict__ ambigCount,
                              ushort* __restrict__ ch,
                              ushort* __restrict__ cm, int nch) {
  __shared__ float row[DIM];
  const int k = blockIdx.x, t = threadIdx.x;   // 512 threads, t = dim
  {
#pragma clang fp contract(off)
    float s = 0.f;
    for (int c = 0; c < nch; c++)
      s = s + part[((size_t)k * nch + c) * DIM + t];
    float mean = s / (float)counts[k];         // cnt==0 -> NaN, matches ref
    ctrNext[(size_t)k * DIM + t] = mean;
    row[t] = mean;
  }
  {
    ushort h, m;
    split2(row[t], h, m);
    ch[(size_t)k * DIM + t] = h;
    cm[(size_t)k * DIM + t] = m;
  }
  __syncthreads();
  if (t == 0) {
#pragma clang fp contract(off)
    float s = 0.f;
    for (int j = 0; j < DIM; j++) {
      float v = row[j];
      float p = v * v;
      s = s + p;
    }
    cnorm[k] = s;
  }
  if (t == 1 && k == 0) *ambigCount = 0;
}

// ---------------- host ----------------
static inline void run_sort(unsigned long long* d, hipStream_t stream) {
  bitonic_local_start<<<32, 1024, 0, stream>>>(d);
  for (int k = 4096; k <= 65536; k <<= 1) {
    for (int j = k >> 1; j >= 2048; j >>= 1)
      bitonic_global_step<<<128, 256, 0, stream>>>(d, k, j);
    bitonic_local<<<32, 1024, 0, stream>>>(d, k);
  }
}

extern "C" void kernel_launch(void* const* d_in, const int* in_sizes, int n_in,
                              void* d_out, int out_size, void* d_ws, size_t ws_size,
                              hipStream_t stream) {
  const float* x = (const float*)d_in[0];
  float* out = (float*)d_out;

  char* p = (char*)d_ws;
  size_t used = 0;
  auto alloc = [&](size_t bytes) {
    char* r = p;
    size_t rb = (bytes + 255) & ~(size_t)255;
    p += rb; used += rb;
    return r;
  };
  unsigned long long* keyA = (unsigned long long*)alloc(N_PTS * 8);
  unsigned long long* keyB = (unsigned long long*)alloc(N_PTS * 8);
  uint32_t* perm1          = (uint32_t*)alloc(N_PTS * 4);
  int* assign              = (int*)alloc(N_PTS * 4);
  int* blockHist           = (int*)alloc(K_CL * 256 * 4);
  int* clusterStart        = (int*)alloc(K_CL * 4);
  int* counts              = (int*)alloc(K_CL * 4);
  int* sortedIdx           = (int*)alloc(N_PTS * 4);
  float* ctrA              = (float*)alloc(K_CL * DIM * 4);
  float* ctrB              = (float*)alloc(K_CL * DIM * 4);
  float* cnorm             = (float*)alloc(K_CL * 4);
  ushort* ch               = (ushort*)alloc((size_t)K_CL * DIM * 2);
  ushort* cm               = (ushort*)alloc((size_t)K_CL * DIM * 2);
  int* ambigCount          = (int*)alloc(4);
  int* ambigList           = (int*)alloc(N_PTS * 4);

  // Chunk count for segsum: 64 if workspace allows, else 8.
  const size_t part64 = (size_t)K_CL * 64 * DIM * 4;   // 33.5 MB
  int nch = (ws_size >= used + part64 + 256) ? 64 : 8;
  float* part = (float*)alloc((size_t)K_CL * nch * DIM * 4);

  // Partitionable (foldlike) threefry split: split(key)[j] = hash(key,(0,j)).
  uint32_t k1a, k1b, s1a, s1b;
  tf2x32(0u, 1u, 0u, 0u, &k1a, &k1b);
  tf2x32(0u, 1u, 0u, 1u, &s1a, &s1b);
  uint32_t k2a, k2b, s2a, s2b;
  tf2x32(k1a, k1b, 0u, 0u, &k2a, &k2b);
  tf2x32(k1a, k1b, 0u, 1u, &s2a, &s2b);

  genbits_kernel<<<256, 256, 0, stream>>>(keyA, s1a, s1b);
  run_sort(keyA, stream);
  extract_low_kernel<<<256, 256, 0, stream>>>(keyA, perm1);
  genbits_kernel<<<256, 256, 0, stream>>>(keyB, s2a, s2b);
  run_sort(keyB, stream);
  init_centers_kernel<<<K_CL, DIM, 0, stream>>>(keyB, perm1, x, ctrA);
  prep_kernel<<<K_CL, 256, 0, stream>>>(ctrA, cnorm, ambigCount, ch, cm);

  float* cur = ctrA;
  for (int it = 0; it < ITERS; ++it) {
    assign_mfma_kernel<<<N_PTS / BM, 256, 0, stream>>>(x, ch, cm, cnorm, assign,
                                                       ambigCount, ambigList);
    refine_kernel<<<1024, 256, 0, stream>>>(x, cur, cnorm, ambigList, ambigCount, assign);
    hist_kernel<<<256, 256, 0, stream>>>(assign, blockHist);
    scan_blocks_kernel<<<256, 256, 0, stream>>>(blockHist, counts);
    scan_clusters_kernel<<<1, 256, 0, stream>>>(counts, clusterStart);
    scatter_kernel<<<256, 256, 0, stream>>>(assign, blockHist, clusterStart, sortedIdx);
    segsum_part_kernel<<<K_CL * nch, DIM, 0, stream>>>(x, sortedIdx, clusterStart,
                                                       counts, part, nch);
    if (it < ITERS - 1) {
      float* next = (it & 1) ? ctrB : ctrA == ctrA && it == 0 ? ctrB : ctrA;
      // simple ping-pong: even it -> ctrB, odd it -> ctrA
      next = (it & 1) ? ctrA : ctrB;
      update_kernel<<<K_CL, DIM, 0, stream>>>(part, counts, next, cnorm,
                                              ambigCount, ch, cm, nch);
      cur = next;
    } else {
      segsum_final_kernel<<<K_CL, DIM, 0, stream>>>(part, counts, out, nch);
    }
  }
}

// Round 19
// 6533.970 us; speedup vs baseline: 1.1053x; 1.0182x over previous
//
#include <hip/hip_runtime.h>
#include <hip/hip_bf16.h>
#include <stdint.h>

#define N_PTS   65536
#define DIM     512
#define K_CL    256
#define ITERS   25
#define BM      64         // points per block in assign
#define TAU     1e-2f      // ambiguity margin; fast-path err max ~1e-3 << TAU/2

typedef __attribute__((ext_vector_type(8))) short  bf16x8;   // 8 bf16 (4 VGPRs)
typedef __attribute__((ext_vector_type(4))) float  f32x4;

// ---------------- Threefry-2x32 (JAX-exact, 20 rounds) ----------------
__host__ __device__ static inline uint32_t rotl32(uint32_t x, int d) {
  return (x << d) | (x >> (32 - d));
}

__host__ __device__ static inline void tf2x32(uint32_t k0, uint32_t k1,
                                              uint32_t x0, uint32_t x1,
                                              uint32_t* o0, uint32_t* o1) {
  const uint32_t ks0 = k0, ks1 = k1, ks2 = k0 ^ k1 ^ 0x1BD11BDAu;
  uint32_t v0 = x0 + ks0, v1 = x1 + ks1;
#define TF_ROUND(R) { v0 += v1; v1 = rotl32(v1, R); v1 ^= v0; }
  TF_ROUND(13) TF_ROUND(15) TF_ROUND(26) TF_ROUND(6)
  v0 += ks1; v1 += ks2 + 1u;
  TF_ROUND(17) TF_ROUND(29) TF_ROUND(16) TF_ROUND(24)
  v0 += ks2; v1 += ks0 + 2u;
  TF_ROUND(13) TF_ROUND(15) TF_ROUND(26) TF_ROUND(6)
  v0 += ks0; v1 += ks1 + 3u;
  TF_ROUND(17) TF_ROUND(29) TF_ROUND(16) TF_ROUND(24)
  v0 += ks1; v1 += ks2 + 4u;
  TF_ROUND(13) TF_ROUND(15) TF_ROUND(26) TF_ROUND(6)
  v0 += ks2; v1 += ks0 + 5u;
#undef TF_ROUND
  *o0 = v0; *o1 = v1;
}

// Partitionable random_bits (32-bit): bits[i] = y0 ^ y1 of hash(key,(0,i)).
__global__ void genbits_kernel(unsigned long long* __restrict__ keyarr,
                               uint32_t k0, uint32_t k1) {
  int i = blockIdx.x * 256 + threadIdx.x;
  uint32_t y0, y1;
  tf2x32(k0, k1, 0u, (uint32_t)i, &y0, &y1);
  uint32_t bits = y0 ^ y1;
  keyarr[i] = ((unsigned long long)bits << 32) | (uint32_t)i;
}

// ---- Bitonic sort, identical comparison network, split across launches ----
__global__ void bitonic_global_step(unsigned long long* __restrict__ d,
                                    int k, int j) {
  int t = blockIdx.x * 256 + threadIdx.x;   // 0..32767
  int low = t & (j - 1);
  int i   = ((t ^ low) << 1) | low;
  int ixj = i | j;
  bool up = ((i & k) == 0);
  unsigned long long a = d[i], b = d[ixj];
  if ((a > b) == up) { d[i] = b; d[ixj] = a; }
}

__global__ void bitonic_local_start(unsigned long long* __restrict__ d) {
  __shared__ unsigned long long s[2048];
  const int base = blockIdx.x * 2048;
  for (int u = threadIdx.x; u < 2048; u += 1024) s[u] = d[base + u];
  __syncthreads();
  for (int k = 2; k <= 2048; k <<= 1) {
    for (int j = k >> 1; j > 0; j >>= 1) {
      int t = threadIdx.x;
      int low = t & (j - 1);
      int il  = ((t ^ low) << 1) | low;
      int ixj = il | j;
      bool up = (((base + il) & k) == 0);
      unsigned long long a = s[il], b = s[ixj];
      if ((a > b) == up) { s[il] = b; s[ixj] = a; }
      __syncthreads();
    }
  }
  for (int u = threadIdx.x; u < 2048; u += 1024) d[base + u] = s[u];
}

__global__ void bitonic_local(unsigned long long* __restrict__ d, int k) {
  __shared__ unsigned long long s[2048];
  const int base = blockIdx.x * 2048;
  for (int u = threadIdx.x; u < 2048; u += 1024) s[u] = d[base + u];
  __syncthreads();
  for (int j = 1024; j > 0; j >>= 1) {
    int t = threadIdx.x;
    int low = t & (j - 1);
    int il  = ((t ^ low) << 1) | low;
    int ixj = il | j;
    bool up = (((base + il) & k) == 0);
    unsigned long long a = s[il], b = s[ixj];
    if ((a > b) == up) { s[il] = b; s[ixj] = a; }
    __syncthreads();
  }
  for (int u = threadIdx.x; u < 2048; u += 1024) d[base + u] = s[u];
}

__global__ void extract_low_kernel(const unsigned long long* __restrict__ s,
                                   uint32_t* __restrict__ out) {
  int i = blockIdx.x * 256 + threadIdx.x;
  out[i] = (uint32_t)(s[i] & 0xffffffffULL);
}

__global__ void init_centers_kernel(const unsigned long long* __restrict__ sorted2,
                                    const uint32_t* __restrict__ perm1,
                                    const float* __restrict__ x,
                                    float* __restrict__ ctr) {
  int k = blockIdx.x, d = threadIdx.x;
  uint32_t p   = (uint32_t)(sorted2[k] & 0xffffffffULL);
  uint32_t src = perm1[p];
  ctr[k * DIM + d] = x[(size_t)src * DIM + d];
}

// ---------------- bf16 2-way split helpers ----------------
__device__ static inline ushort f2bf(float f) {
  __hip_bfloat16 b = __float2bfloat16(f);
  return *reinterpret_cast<ushort*>(&b);
}
__device__ static inline float bf2f(ushort u) {
  __hip_bfloat16 b = *reinterpret_cast<__hip_bfloat16*>(&u);
  return __bfloat162float(b);
}
__device__ static inline void split2(float v, ushort& h, ushort& m) {
#pragma clang fp contract(off)
  h = f2bf(v);
  float r1 = v - bf2f(h);
  m = f2bf(r1);
}

// ---------------- iteration-0 prep (cnorm + csplit + zero) ----------------
__global__ void prep_kernel(const float* __restrict__ ctr,
                            float* __restrict__ cnorm,
                            int* __restrict__ ambigCount,
                            ushort* __restrict__ ch,
                            ushort* __restrict__ cm) {
  __shared__ float row[DIM];
  const int k = blockIdx.x, t = threadIdx.x;
  if (k == 0 && t == 0) *ambigCount = 0;
  row[t]       = ctr[(size_t)k * DIM + t];
  row[t + 256] = ctr[(size_t)k * DIM + t + 256];
  __syncthreads();
#pragma unroll
  for (int u = t; u < DIM; u += 256) {
    ushort h, m;
    split2(row[u], h, m);
    ch[(size_t)k * DIM + u] = h;
    cm[(size_t)k * DIM + u] = m;
  }
  if (t == 0) {
#pragma clang fp contract(off)
    float s = 0.f;
    for (int j = 0; j < DIM; j++) {
      float v = row[j];
      float p = v * v;
      s = s + p;
    }
    cnorm[k] = s;
  }
}

// argmin fold: NaN is minimal; first index wins ties (lexicographic).
__device__ static inline void argmin_pick(float ov, int ok, float& bv, int& bk) {
  bool no = __builtin_isnan(ov), nb = __builtin_isnan(bv);
  bool take;
  if (no != nb)      take = no;
  else if (no)       take = ok < bk;
  else               take = (ov < bv) || (ov == bv && ok < bk);
  if (take) { bv = ov; bk = ok; }
}

// ---- (best, idx, second) triple machinery for margin tracking ----
__device__ static inline bool before3(float a, int ai, float b, int bi) {
  bool na = __builtin_isnan(a), nb = __builtin_isnan(b);
  if (na != nb) return na;
  if (na)       return ai < bi;
  return a < b || (a == b && ai < bi);
}
__device__ static inline float valmin3(float a, float b) {
  if (__builtin_isnan(a) || __builtin_isnan(b)) return __int_as_float(0x7fc00000);
  return fminf(a, b);
}
__device__ static inline void merge3(float ob, int oi, float os,
                                     float& b, int& i, float& s) {
  if (before3(ob, oi, b, i)) { s = valmin3(b, os); b = ob; i = oi; }
  else                        s = valmin3(s, ob);
}

// MFMA distance-GEMM + argmin + margin gate.  r17/r18 structure + B register
// double-buffer: B(k+1) loads issued BEFORE MFMAs of step k (2-step unroll
// with statically-named reg sets).  Values and MFMA order unchanged ->
// bit-identical results.
#define LOAD_B(BH, BM, K0) {                                               \
  size_t rowoff_ = (size_t)(colbase + l15) * DIM + (K0) + l4 * 8;          \
  _Pragma("unroll")                                                        \
  for (int j_ = 0; j_ < 4; j_++) {                                         \
    size_t off_ = rowoff_ + (size_t)j_ * 16 * DIM;                         \
    BH[j_] = *reinterpret_cast<const bf16x8*>(&ch[off_]);                  \
    BM[j_] = *reinterpret_cast<const bf16x8*>(&cm[off_]);                  \
  } }

#define PREFETCH_A(K0) {                                                   \
  v0 = *reinterpret_cast<const float4*>(srcbase + (K0));                   \
  v1 = *reinterpret_cast<const float4*>(srcbase + (K0) + 4); }

#define WRITE_A(BUF) {                                                     \
  float vv_[8] = {v0.x, v0.y, v0.z, v0.w, v1.x, v1.y, v1.z, v1.w};         \
  bf16x8 vh_, vm_;                                                         \
  _Pragma("unroll")                                                        \
  for (int q_ = 0; q_ < 8; q_++) {                                         \
    ushort h_, m_;                                                         \
    split2(vv_[q_], h_, m_);                                               \
    vh_[q_] = (short)h_; vm_[q_] = (short)m_;                              \
  }                                                                        \
  *reinterpret_cast<bf16x8*>(&ah[BUF][sr][sko]) = vh_;                     \
  *reinterpret_cast<bf16x8*>(&am[BUF][sr][sko]) = vm_; }

#define MFMA_STEP(BUF, BH, BM)                                             \
  _Pragma("unroll")                                                        \
  for (int i_ = 0; i_ < 4; i_++) {                                         \
    int r_ = i_ * 16 + l15, ko_ = l4 * 8;                                  \
    bf16x8 fah_ = *reinterpret_cast<bf16x8*>(&ah[BUF][r_][ko_]);           \
    bf16x8 fam_ = *reinterpret_cast<bf16x8*>(&am[BUF][r_][ko_]);           \
    _Pragma("unroll")                                                      \
    for (int j_ = 0; j_ < 4; j_++) {                                       \
      acc[i_][j_] = __builtin_amdgcn_mfma_f32_16x16x32_bf16(fah_, BH[j_], acc[i_][j_], 0, 0, 0); \
      acc[i_][j_] = __builtin_amdgcn_mfma_f32_16x16x32_bf16(fah_, BM[j_], acc[i_][j_], 0, 0, 0); \
      acc[i_][j_] = __builtin_amdgcn_mfma_f32_16x16x32_bf16(fam_, BH[j_], acc[i_][j_], 0, 0, 0); \
    } }

__launch_bounds__(256, 4)
__global__ void assign_mfma_kernel(const float* __restrict__ x,
                                   const ushort* __restrict__ ch,
                                   const ushort* __restrict__ cm,
                                   const float* __restrict__ cnorm,
                                   int* __restrict__ assign,
                                   int* __restrict__ ambigCount,
                                   int* __restrict__ ambigList) {
  __shared__ __align__(16) ushort ah[2][64][40], am[2][64][40];   // 20.5 KB
  __shared__ float  redv[4][64];
  __shared__ int    redi[4][64];
  __shared__ float  reds[4][64];

  const int t = threadIdx.x;
  const int w = t >> 6;
  const int lane = t & 63;
  const int m0 = blockIdx.x * BM;
  const int colbase = w * 64;
  const int l15 = lane & 15, l4 = lane >> 4;
  const int sr = t >> 2, sko = (t & 3) * 8;        // staging map
  const float* srcbase = &x[(size_t)(m0 + sr) * DIM + sko];

  f32x4 acc[4][4];
#pragma unroll
  for (int i = 0; i < 4; i++)
#pragma unroll
    for (int j = 0; j < 4; j++) acc[i][j] = (f32x4)(0.f);

  bf16x8 bhA[4], bmA[4], bhB[4], bmB[4];
  float4 v0, v1;

  // prologue: stage A(k=0) into buf 0; load B(k=0) into set A
  PREFETCH_A(0);
  WRITE_A(0);
  LOAD_B(bhA, bmA, 0);
  __syncthreads();

#pragma unroll
  for (int ks2 = 0; ks2 < 16; ks2 += 2) {
    const int k0 = ks2 * 32;
    // ---- even step (ks = ks2): A in buf0, B in set A ----
    PREFETCH_A(k0 + 32);                 // A for ks2+1 (always exists)
    LOAD_B(bhB, bmB, k0 + 32);           // B for ks2+1, issued BEFORE MFMAs
    MFMA_STEP(0, bhA, bmA);
    WRITE_A(1);
    __syncthreads();
    // ---- odd step (ks = ks2+1): A in buf1, B in set B ----
    if (ks2 + 2 < 16) {
      PREFETCH_A(k0 + 64);
      LOAD_B(bhA, bmA, k0 + 64);
    }
    MFMA_STEP(1, bhB, bmB);
    if (ks2 + 2 < 16) WRITE_A(0);
    __syncthreads();
  }

  // ---- epilogue: d2 = cnorm - 2*dot; (best, idx, second); margin gate ----
  {
#pragma clang fp contract(off)
    float cn[4];
#pragma unroll
    for (int j = 0; j < 4; j++) cn[j] = cnorm[colbase + j * 16 + l15];

#pragma unroll
    for (int i = 0; i < 4; i++) {
#pragma unroll
      for (int reg = 0; reg < 4; reg++) {
        float bb = __int_as_float(0x7f800000);  // +inf
        int   bi = 0x7fffffff;
        float bs = __int_as_float(0x7f800000);
#pragma unroll
        for (int j = 0; j < 4; j++) {
          int col = colbase + j * 16 + l15;
          float d2 = cn[j] - 2.0f * acc[i][j][reg];
          merge3(d2, col, __int_as_float(0x7f800000), bb, bi, bs);
        }
#pragma unroll
        for (int s = 1; s < 16; s <<= 1) {
          float ob = __shfl_xor(bb, s);
          int   oi = __shfl_xor(bi, s);
          float os = __shfl_xor(bs, s);
          merge3(ob, oi, os, bb, bi, bs);
        }
        if (l15 == 0) {
          int row = i * 16 + l4 * 4 + reg;
          redv[w][row] = bb; redi[w][row] = bi; reds[w][row] = bs;
        }
      }
    }
    __syncthreads();
    if (t < 64) {
      float bb = __int_as_float(0x7f800000);
      int   bi = 0x7fffffff;
      float bs = __int_as_float(0x7f800000);
#pragma unroll
      for (int w2 = 0; w2 < 4; w2++)
        merge3(redv[w2][t], redi[w2][t], reds[w2][t], bb, bi, bs);
      assign[m0 + t] = bi;
      float margin = bs - bb;
      if (!(margin > TAU)) {                 // NaN margin also flags
        int pos = atomicAdd(ambigCount, 1);
        if (pos < N_PTS) ambigList[pos] = m0 + t;
      }
    }
  }
}

// Exact recheck of ambiguous points with the r5 bit-exact scheme.
__launch_bounds__(256)
__global__ void refine_kernel(const float* __restrict__ x,
                              const float* __restrict__ ctr,
                              const float* __restrict__ cnorm,
                              const int* __restrict__ ambigList,
                              const int* __restrict__ ambigCount,
                              int* __restrict__ assign) {
  __shared__ float xrow[DIM];
  __shared__ float cs[K_CL][33];
  __shared__ float rv[K_CL];
  __shared__ int   ri[K_CL];
  const int t = threadIdx.x;
  int cnt = *ambigCount; if (cnt > N_PTS) cnt = N_PTS;
  for (int a = blockIdx.x; a < cnt; a += gridDim.x) {
    int pt = ambigList[a];
    __syncthreads();
    for (int u = t; u < DIM; u += 256) xrow[u] = x[(size_t)pt * DIM + u];
    float accA = 0.f, accB = 0.f;
    for (int c = 0; c < 16; c++) {
      __syncthreads();
      for (int u = t; u < K_CL * 32; u += 256) {
        int k = u >> 5, j = u & 31;
        cs[k][j] = ctr[(size_t)k * DIM + c * 32 + j];
      }
      __syncthreads();
      {
#pragma clang fp contract(off)
        float s = (c < 9) ? accA : accB;
        for (int j = 0; j < 32; j++) {
          float pv = xrow[c * 32 + j] * cs[t][j];
          s = s + pv;
        }
        if (c < 9) accA = s; else accB = s;
      }
    }
    float d2;
    {
#pragma clang fp contract(off)
      float dot = accA + accB;
      float tw = 2.0f * dot;
      d2 = cnorm[t] - tw;
    }
    rv[t] = d2; ri[t] = t;
    __syncthreads();
    for (int st = 128; st >= 1; st >>= 1) {
      if (t < st) argmin_pick(rv[t + st], ri[t + st], rv[t], ri[t]);
      __syncthreads();
    }
    if (t == 0) assign[pt] = ri[0];
  }
}

// Counting sort stage 1: per-block histogram, BLOCK-major output (coalesced).
__global__ void hist_kernel(const int* __restrict__ assign, int* __restrict__ blockHist) {
  __shared__ int h[K_CL];
  int b = blockIdx.x, t = threadIdx.x;
  h[t] = 0; __syncthreads();
  int k = assign[b * 256 + t];
  atomicAdd(&h[k], 1);
  __syncthreads();
  blockHist[b * 256 + t] = h[t];
}

// Stage 2a: per-cluster exclusive scan over the 256 block values (parallel).
__global__ void scan_blocks_kernel(int* __restrict__ blockHist,
                                   int* __restrict__ counts) {
  __shared__ int v[256];
  int k = blockIdx.x, b = threadIdx.x;
  int x = blockHist[b * 256 + k];
  v[b] = x;
  __syncthreads();
  for (int s = 1; s < 256; s <<= 1) {
    int add = (b >= s) ? v[b - s] : 0;
    __syncthreads();
    v[b] += add;
    __syncthreads();
  }
  blockHist[b * 256 + k] = v[b] - x;
  if (b == 255) counts[k] = v[255];
}

// Stage 2b: exclusive scan of cluster totals -> clusterStart. One block.
__global__ void scan_clusters_kernel(const int* __restrict__ counts,
                                     int* __restrict__ clusterStart) {
  __shared__ int v[256];
  int k = threadIdx.x;
  int x = counts[k];
  v[k] = x;
  __syncthreads();
  for (int s = 1; s < 256; s <<= 1) {
    int add = (k >= s) ? v[k - s] : 0;
    __syncthreads();
    v[k] += add;
    __syncthreads();
  }
  clusterStart[k] = v[k] - x;
}

// Stage 3: stable scatter of point indices into cluster-sorted order.
__global__ void scatter_kernel(const int* __restrict__ assign,
                               const int* __restrict__ blockHist,
                               const int* __restrict__ clusterStart,
                               int* __restrict__ sortedIdx) {
  __shared__ int la[256];
  int b = blockIdx.x, t = threadIdx.x;
  int n = b * 256 + t;
  int k = assign[n];
  la[t] = k; __syncthreads();
  int rank = 0;
  for (int u = 0; u < t; u++) rank += (la[u] == k) ? 1 : 0;
  sortedIdx[clusterStart[k] + blockHist[b * 256 + k] + rank] = n;
}

// Stage 4a: per-(cluster, chunk) partial sums, nch chunks per cluster.
__global__ void segsum_part_kernel(const float* __restrict__ x,
                                   const int* __restrict__ sortedIdx,
                                   const int* __restrict__ clusterStart,
                                   const int* __restrict__ counts,
                                   float* __restrict__ part, int nch) {
#pragma clang fp contract(off)
  int k = blockIdx.x / nch;      // cluster
  int c = blockIdx.x - k * nch;  // chunk
  int d = threadIdx.x;
  int start = clusterStart[k], cnt = counts[k];
  int ch = (cnt + nch - 1) / nch;
  int b0 = c * ch;
  int b1 = b0 + ch; if (b1 > cnt) b1 = cnt;
  float s = 0.f;
  for (int i = b0; i < b1; i++) {
    int idx = sortedIdx[start + i];
    s = s + x[(size_t)idx * DIM + d];
  }
  part[((size_t)k * nch + c) * DIM + d] = s;
}

// Stage 4b (last iter): combine chunks ascending, divide -> out.
__global__ void segsum_final_kernel(const float* __restrict__ part,
                                    const int* __restrict__ counts,
                                    float* __restrict__ out, int nch) {
#pragma clang fp contract(off)
  int k = blockIdx.x, d = threadIdx.x;
  float s = 0.f;
  for (int c = 0; c < nch; c++)
    s = s + part[((size_t)k * nch + c) * DIM + d];
  out[k * DIM + d] = s / (float)counts[k];   // cnt==0 -> NaN, matches ref
}

// Stage 4b + prep fused (iters 0..ITERS-2): combine chunks -> next centers,
// split to bf16 planes, cnorm (same strict-sequential order), zero ambig.
__global__ void update_kernel(const float* __restrict__ part,
                              const int* __restrict__ counts,
                              float* __restrict__ ctrNext,
                              float* __restrict__ cnorm,
                              int* __restrict__ ambigCount,
                              ushort* __restrict__ ch,
                              ushort* __restrict__ cm, int nch) {
  __shared__ float row[DIM];
  const int k = blockIdx.x, t = threadIdx.x;   // 512 threads, t = dim
  {
#pragma clang fp contract(off)
    float s = 0.f;
    for (int c = 0; c < nch; c++)
      s = s + part[((size_t)k * nch + c) * DIM + t];
    float mean = s / (float)counts[k];         // cnt==0 -> NaN, matches ref
    ctrNext[(size_t)k * DIM + t] = mean;
    row[t] = mean;
  }
  {
    ushort h, m;
    split2(row[t], h, m);
    ch[(size_t)k * DIM + t] = h;
    cm[(size_t)k * DIM + t] = m;
  }
  __syncthreads();
  if (t == 0) {
#pragma clang fp contract(off)
    float s = 0.f;
    for (int j = 0; j < DIM; j++) {
      float v = row[j];
      float p = v * v;
      s = s + p;
    }
    cnorm[k] = s;
  }
  if (t == 1 && k == 0) *ambigCount = 0;
}

// ---------------- host ----------------
static inline void run_sort(unsigned long long* d, hipStream_t stream) {
  bitonic_local_start<<<32, 1024, 0, stream>>>(d);
  for (int k = 4096; k <= 65536; k <<= 1) {
    for (int j = k >> 1; j >= 2048; j >>= 1)
      bitonic_global_step<<<128, 256, 0, stream>>>(d, k, j);
    bitonic_local<<<32, 1024, 0, stream>>>(d, k);
  }
}

extern "C" void kernel_launch(void* const* d_in, const int* in_sizes, int n_in,
                              void* d_out, int out_size, void* d_ws, size_t ws_size,
                              hipStream_t stream) {
  const float* x = (const float*)d_in[0];
  float* out = (float*)d_out;

  char* p = (char*)d_ws;
  size_t used = 0;
  auto alloc = [&](size_t bytes) {
    char* r = p;
    size_t rb = (bytes + 255) & ~(size_t)255;
    p += rb; used += rb;
    return r;
  };
  unsigned long long* keyA = (unsigned long long*)alloc(N_PTS * 8);
  unsigned long long* keyB = (unsigned long long*)alloc(N_PTS * 8);
  uint32_t* perm1          = (uint32_t*)alloc(N_PTS * 4);
  int* assign              = (int*)alloc(N_PTS * 4);
  int* blockHist           = (int*)alloc(K_CL * 256 * 4);
  int* clusterStart        = (int*)alloc(K_CL * 4);
  int* counts              = (int*)alloc(K_CL * 4);
  int* sortedIdx           = (int*)alloc(N_PTS * 4);
  float* ctrA              = (float*)alloc(K_CL * DIM * 4);
  float* ctrB              = (float*)alloc(K_CL * DIM * 4);
  float* cnorm             = (float*)alloc(K_CL * 4);
  ushort* ch               = (ushort*)alloc((size_t)K_CL * DIM * 2);
  ushort* cm               = (ushort*)alloc((size_t)K_CL * DIM * 2);
  int* ambigCount          = (int*)alloc(4);
  int* ambigList           = (int*)alloc(N_PTS * 4);

  // Chunk count for segsum: 64 if workspace allows, else 8.
  const size_t part64 = (size_t)K_CL * 64 * DIM * 4;   // 33.5 MB
  int nch = (ws_size >= used + part64 + 256) ? 64 : 8;
  float* part = (float*)alloc((size_t)K_CL * nch * DIM * 4);

  // Partitionable (foldlike) threefry split: split(key)[j] = hash(key,(0,j)).
  uint32_t k1a, k1b, s1a, s1b;
  tf2x32(0u, 1u, 0u, 0u, &k1a, &k1b);
  tf2x32(0u, 1u, 0u, 1u, &s1a, &s1b);
  uint32_t k2a, k2b, s2a, s2b;
  tf2x32(k1a, k1b, 0u, 0u, &k2a, &k2b);
  tf2x32(k1a, k1b, 0u, 1u, &s2a, &s2b);

  genbits_kernel<<<256, 256, 0, stream>>>(keyA, s1a, s1b);
  run_sort(keyA, stream);
  extract_low_kernel<<<256, 256, 0, stream>>>(keyA, perm1);
  genbits_kernel<<<256, 256, 0, stream>>>(keyB, s2a, s2b);
  run_sort(keyB, stream);
  init_centers_kernel<<<K_CL, DIM, 0, stream>>>(keyB, perm1, x, ctrA);
  prep_kernel<<<K_CL, 256, 0, stream>>>(ctrA, cnorm, ambigCount, ch, cm);

  float* cur = ctrA;
  for (int it = 0; it < ITERS; ++it) {
    assign_mfma_kernel<<<N_PTS / BM, 256, 0, stream>>>(x, ch, cm, cnorm, assign,
                                                       ambigCount, ambigList);
    refine_kernel<<<1024, 256, 0, stream>>>(x, cur, cnorm, ambigList, ambigCount, assign);
    hist_kernel<<<256, 256, 0, stream>>>(assign, blockHist);
    scan_blocks_kernel<<<256, 256, 0, stream>>>(blockHist, counts);
    scan_clusters_kernel<<<1, 256, 0, stream>>>(counts, clusterStart);
    scatter_kernel<<<256, 256, 0, stream>>>(assign, blockHist, clusterStart, sortedIdx);
    segsum_part_kernel<<<K_CL * nch, DIM, 0, stream>>>(x, sortedIdx, clusterStart,
                                                       counts, part, nch);
    if (it < ITERS - 1) {
      float* next = (it & 1) ? ctrA : ctrB;
      update_kernel<<<K_CL, DIM, 0, stream>>>(part, counts, next, cnorm,
                                              ambigCount, ch, cm, nch);
      cur = next;
    } else {
      segsum_final_kernel<<<K_CL, DIM, 0, stream>>>(part, counts, out, nch);
    }
  }
}

// Round 20
// 6518.838 us; speedup vs baseline: 1.1079x; 1.0023x over previous
//
#include <hip/hip_runtime.h>
#include <hip/hip_bf16.h>
#include <stdint.h>

#define N_PTS   65536
#define DIM     512
#define K_CL    256
#define ITERS   25
#define BM      64         // points per block in assign
#define TAU     1e-2f      // ambiguity margin; fast-path err max ~1e-3 << TAU/2

typedef __attribute__((ext_vector_type(8))) short  bf16x8;   // 8 bf16 (4 VGPRs)
typedef __attribute__((ext_vector_type(4))) float  f32x4;

// ---------------- Threefry-2x32 (JAX-exact, 20 rounds) ----------------
__host__ __device__ static inline uint32_t rotl32(uint32_t x, int d) {
  return (x << d) | (x >> (32 - d));
}

__host__ __device__ static inline void tf2x32(uint32_t k0, uint32_t k1,
                                              uint32_t x0, uint32_t x1,
                                              uint32_t* o0, uint32_t* o1) {
  const uint32_t ks0 = k0, ks1 = k1, ks2 = k0 ^ k1 ^ 0x1BD11BDAu;
  uint32_t v0 = x0 + ks0, v1 = x1 + ks1;
#define TF_ROUND(R) { v0 += v1; v1 = rotl32(v1, R); v1 ^= v0; }
  TF_ROUND(13) TF_ROUND(15) TF_ROUND(26) TF_ROUND(6)
  v0 += ks1; v1 += ks2 + 1u;
  TF_ROUND(17) TF_ROUND(29) TF_ROUND(16) TF_ROUND(24)
  v0 += ks2; v1 += ks0 + 2u;
  TF_ROUND(13) TF_ROUND(15) TF_ROUND(26) TF_ROUND(6)
  v0 += ks0; v1 += ks1 + 3u;
  TF_ROUND(17) TF_ROUND(29) TF_ROUND(16) TF_ROUND(24)
  v0 += ks1; v1 += ks2 + 4u;
  TF_ROUND(13) TF_ROUND(15) TF_ROUND(26) TF_ROUND(6)
  v0 += ks2; v1 += ks0 + 5u;
#undef TF_ROUND
  *o0 = v0; *o1 = v1;
}

// Partitionable random_bits (32-bit): bits[i] = y0 ^ y1 of hash(key,(0,i)).
__global__ void genbits_kernel(unsigned long long* __restrict__ keyarr,
                               uint32_t k0, uint32_t k1) {
  int i = blockIdx.x * 256 + threadIdx.x;
  uint32_t y0, y1;
  tf2x32(k0, k1, 0u, (uint32_t)i, &y0, &y1);
  uint32_t bits = y0 ^ y1;
  keyarr[i] = ((unsigned long long)bits << 32) | (uint32_t)i;
}

// ---- Bitonic sort, identical comparison network, split across launches ----
__global__ void bitonic_global_step(unsigned long long* __restrict__ d,
                                    int k, int j) {
  int t = blockIdx.x * 256 + threadIdx.x;   // 0..32767
  int low = t & (j - 1);
  int i   = ((t ^ low) << 1) | low;
  int ixj = i | j;
  bool up = ((i & k) == 0);
  unsigned long long a = d[i], b = d[ixj];
  if ((a > b) == up) { d[i] = b; d[ixj] = a; }
}

__global__ void bitonic_local_start(unsigned long long* __restrict__ d) {
  __shared__ unsigned long long s[2048];
  const int base = blockIdx.x * 2048;
  for (int u = threadIdx.x; u < 2048; u += 1024) s[u] = d[base + u];
  __syncthreads();
  for (int k = 2; k <= 2048; k <<= 1) {
    for (int j = k >> 1; j > 0; j >>= 1) {
      int t = threadIdx.x;
      int low = t & (j - 1);
      int il  = ((t ^ low) << 1) | low;
      int ixj = il | j;
      bool up = (((base + il) & k) == 0);
      unsigned long long a = s[il], b = s[ixj];
      if ((a > b) == up) { s[il] = b; s[ixj] = a; }
      __syncthreads();
    }
  }
  for (int u = threadIdx.x; u < 2048; u += 1024) d[base + u] = s[u];
}

__global__ void bitonic_local(unsigned long long* __restrict__ d, int k) {
  __shared__ unsigned long long s[2048];
  const int base = blockIdx.x * 2048;
  for (int u = threadIdx.x; u < 2048; u += 1024) s[u] = d[base + u];
  __syncthreads();
  for (int j = 1024; j > 0; j >>= 1) {
    int t = threadIdx.x;
    int low = t & (j - 1);
    int il  = ((t ^ low) << 1) | low;
    int ixj = il | j;
    bool up = (((base + il) & k) == 0);
    unsigned long long a = s[il], b = s[ixj];
    if ((a > b) == up) { s[il] = b; s[ixj] = a; }
    __syncthreads();
  }
  for (int u = threadIdx.x; u < 2048; u += 1024) d[base + u] = s[u];
}

__global__ void extract_low_kernel(const unsigned long long* __restrict__ s,
                                   uint32_t* __restrict__ out) {
  int i = blockIdx.x * 256 + threadIdx.x;
  out[i] = (uint32_t)(s[i] & 0xffffffffULL);
}

__global__ void init_centers_kernel(const unsigned long long* __restrict__ sorted2,
                                    const uint32_t* __restrict__ perm1,
                                    const float* __restrict__ x,
                                    float* __restrict__ ctr) {
  int k = blockIdx.x, d = threadIdx.x;
  uint32_t p   = (uint32_t)(sorted2[k] & 0xffffffffULL);
  uint32_t src = perm1[p];
  ctr[k * DIM + d] = x[(size_t)src * DIM + d];
}

// ---------------- bf16 2-way split helpers ----------------
__device__ static inline ushort f2bf(float f) {
  __hip_bfloat16 b = __float2bfloat16(f);
  return *reinterpret_cast<ushort*>(&b);
}
__device__ static inline float bf2f(ushort u) {
  __hip_bfloat16 b = *reinterpret_cast<__hip_bfloat16*>(&u);
  return __bfloat162float(b);
}
__device__ static inline void split2(float v, ushort& h, ushort& m) {
#pragma clang fp contract(off)
  h = f2bf(v);
  float r1 = v - bf2f(h);
  m = f2bf(r1);
}

// ---------------- iteration-0 prep (cnorm + csplit + zero) ----------------
__global__ void prep_kernel(const float* __restrict__ ctr,
                            float* __restrict__ cnorm,
                            int* __restrict__ ambigCount,
                            ushort* __restrict__ ch,
                            ushort* __restrict__ cm) {
  __shared__ float row[DIM];
  const int k = blockIdx.x, t = threadIdx.x;
  if (k == 0 && t == 0) *ambigCount = 0;
  row[t]       = ctr[(size_t)k * DIM + t];
  row[t + 256] = ctr[(size_t)k * DIM + t + 256];
  __syncthreads();
#pragma unroll
  for (int u = t; u < DIM; u += 256) {
    ushort h, m;
    split2(row[u], h, m);
    ch[(size_t)k * DIM + u] = h;
    cm[(size_t)k * DIM + u] = m;
  }
  if (t == 0) {
#pragma clang fp contract(off)
    float s = 0.f;
    for (int j = 0; j < DIM; j++) {
      float v = row[j];
      float p = v * v;
      s = s + p;
    }
    cnorm[k] = s;
  }
}

// argmin fold: NaN is minimal; first index wins ties (lexicographic).
__device__ static inline void argmin_pick(float ov, int ok, float& bv, int& bk) {
  bool no = __builtin_isnan(ov), nb = __builtin_isnan(bv);
  bool take;
  if (no != nb)      take = no;
  else if (no)       take = ok < bk;
  else               take = (ov < bv) || (ov == bv && ok < bk);
  if (take) { bv = ov; bk = ok; }
}

// ---- (best, idx, second) triple machinery for margin tracking ----
__device__ static inline bool before3(float a, int ai, float b, int bi) {
  bool na = __builtin_isnan(a), nb = __builtin_isnan(b);
  if (na != nb) return na;
  if (na)       return ai < bi;
  return a < b || (a == b && ai < bi);
}
__device__ static inline float valmin3(float a, float b) {
  if (__builtin_isnan(a) || __builtin_isnan(b)) return __int_as_float(0x7fc00000);
  return fminf(a, b);
}
__device__ static inline void merge3(float ob, int oi, float os,
                                     float& b, int& i, float& s) {
  if (before3(ob, oi, b, i)) { s = valmin3(b, os); b = ob; i = oi; }
  else                        s = valmin3(s, ob);
}

// MFMA distance-GEMM + argmin + margin gate.  r19 structure + RAW BARRIERS:
// k-loop barriers drain lgkmcnt only (LDS correctness) while global B/A
// prefetch loads stay in flight across the barrier (reg-staged LDS writes
// are lgkm-tracked, so vmcnt need not drain).  Math order unchanged ->
// bit-identical results.
#define LOAD_B(BH, BM, K0) {                                               \
  size_t rowoff_ = (size_t)(colbase + l15) * DIM + (K0) + l4 * 8;          \
  _Pragma("unroll")                                                        \
  for (int j_ = 0; j_ < 4; j_++) {                                         \
    size_t off_ = rowoff_ + (size_t)j_ * 16 * DIM;                         \
    BH[j_] = *reinterpret_cast<const bf16x8*>(&ch[off_]);                  \
    BM[j_] = *reinterpret_cast<const bf16x8*>(&cm[off_]);                  \
  } }

#define PREFETCH_A(K0) {                                                   \
  v0 = *reinterpret_cast<const float4*>(srcbase + (K0));                   \
  v1 = *reinterpret_cast<const float4*>(srcbase + (K0) + 4); }

#define WRITE_A(BUF) {                                                     \
  float vv_[8] = {v0.x, v0.y, v0.z, v0.w, v1.x, v1.y, v1.z, v1.w};         \
  bf16x8 vh_, vm_;                                                         \
  _Pragma("unroll")                                                        \
  for (int q_ = 0; q_ < 8; q_++) {                                         \
    ushort h_, m_;                                                         \
    split2(vv_[q_], h_, m_);                                               \
    vh_[q_] = (short)h_; vm_[q_] = (short)m_;                              \
  }                                                                        \
  *reinterpret_cast<bf16x8*>(&ah[BUF][sr][sko]) = vh_;                     \
  *reinterpret_cast<bf16x8*>(&am[BUF][sr][sko]) = vm_; }

#define MFMA_STEP(BUF, BH, BM)                                             \
  _Pragma("unroll")                                                        \
  for (int i_ = 0; i_ < 4; i_++) {                                         \
    int r_ = i_ * 16 + l15, ko_ = l4 * 8;                                  \
    bf16x8 fah_ = *reinterpret_cast<bf16x8*>(&ah[BUF][r_][ko_]);           \
    bf16x8 fam_ = *reinterpret_cast<bf16x8*>(&am[BUF][r_][ko_]);           \
    _Pragma("unroll")                                                      \
    for (int j_ = 0; j_ < 4; j_++) {                                       \
      acc[i_][j_] = __builtin_amdgcn_mfma_f32_16x16x32_bf16(fah_, BH[j_], acc[i_][j_], 0, 0, 0); \
      acc[i_][j_] = __builtin_amdgcn_mfma_f32_16x16x32_bf16(fah_, BM[j_], acc[i_][j_], 0, 0, 0); \
      acc[i_][j_] = __builtin_amdgcn_mfma_f32_16x16x32_bf16(fam_, BH[j_], acc[i_][j_], 0, 0, 0); \
    } }

// LDS-only barrier: drain ds ops, let global loads stay in flight.
#define LDS_BARRIER() do {                                                 \
  asm volatile("s_waitcnt lgkmcnt(0)" ::: "memory");                       \
  __builtin_amdgcn_s_barrier();                                            \
} while (0)

__launch_bounds__(256, 4)
__global__ void assign_mfma_kernel(const float* __restrict__ x,
                                   const ushort* __restrict__ ch,
                                   const ushort* __restrict__ cm,
                                   const float* __restrict__ cnorm,
                                   int* __restrict__ assign,
                                   int* __restrict__ ambigCount,
                                   int* __restrict__ ambigList) {
  __shared__ __align__(16) ushort ah[2][64][40], am[2][64][40];   // 20.5 KB
  __shared__ float  redv[4][64];
  __shared__ int    redi[4][64];
  __shared__ float  reds[4][64];

  const int t = threadIdx.x;
  const int w = t >> 6;
  const int lane = t & 63;
  const int m0 = blockIdx.x * BM;
  const int colbase = w * 64;
  const int l15 = lane & 15, l4 = lane >> 4;
  const int sr = t >> 2, sko = (t & 3) * 8;        // staging map
  const float* srcbase = &x[(size_t)(m0 + sr) * DIM + sko];

  f32x4 acc[4][4];
#pragma unroll
  for (int i = 0; i < 4; i++)
#pragma unroll
    for (int j = 0; j < 4; j++) acc[i][j] = (f32x4)(0.f);

  bf16x8 bhA[4], bmA[4], bhB[4], bmB[4];
  float4 v0, v1;

  // prologue: stage A(k=0) into buf 0; load B(k=0) into set A
  PREFETCH_A(0);
  WRITE_A(0);
  LOAD_B(bhA, bmA, 0);
  __syncthreads();

#pragma unroll
  for (int ks2 = 0; ks2 < 16; ks2 += 2) {
    const int k0 = ks2 * 32;
    // ---- even step (ks = ks2): A in buf0, B in set A ----
    PREFETCH_A(k0 + 32);                 // A for ks2+1 (always exists)
    LOAD_B(bhB, bmB, k0 + 32);           // B for ks2+1, issued BEFORE MFMAs
    MFMA_STEP(0, bhA, bmA);
    WRITE_A(1);
    LDS_BARRIER();                       // vmcnt stays in flight
    // ---- odd step (ks = ks2+1): A in buf1, B in set B ----
    if (ks2 + 2 < 16) {
      PREFETCH_A(k0 + 64);
      LOAD_B(bhA, bmA, k0 + 64);
    }
    MFMA_STEP(1, bhB, bmB);
    if (ks2 + 2 < 16) WRITE_A(0);
    LDS_BARRIER();
  }

  // ---- epilogue: d2 = cnorm - 2*dot; (best, idx, second); margin gate ----
  {
#pragma clang fp contract(off)
    float cn[4];
#pragma unroll
    for (int j = 0; j < 4; j++) cn[j] = cnorm[colbase + j * 16 + l15];

#pragma unroll
    for (int i = 0; i < 4; i++) {
#pragma unroll
      for (int reg = 0; reg < 4; reg++) {
        float bb = __int_as_float(0x7f800000);  // +inf
        int   bi = 0x7fffffff;
        float bs = __int_as_float(0x7f800000);
#pragma unroll
        for (int j = 0; j < 4; j++) {
          int col = colbase + j * 16 + l15;
          float d2 = cn[j] - 2.0f * acc[i][j][reg];
          merge3(d2, col, __int_as_float(0x7f800000), bb, bi, bs);
        }
#pragma unroll
        for (int s = 1; s < 16; s <<= 1) {
          float ob = __shfl_xor(bb, s);
          int   oi = __shfl_xor(bi, s);
          float os = __shfl_xor(bs, s);
          merge3(ob, oi, os, bb, bi, bs);
        }
        if (l15 == 0) {
          int row = i * 16 + l4 * 4 + reg;
          redv[w][row] = bb; redi[w][row] = bi; reds[w][row] = bs;
        }
      }
    }
    __syncthreads();
    if (t < 64) {
      float bb = __int_as_float(0x7f800000);
      int   bi = 0x7fffffff;
      float bs = __int_as_float(0x7f800000);
#pragma unroll
      for (int w2 = 0; w2 < 4; w2++)
        merge3(redv[w2][t], redi[w2][t], reds[w2][t], bb, bi, bs);
      assign[m0 + t] = bi;
      float margin = bs - bb;
      if (!(margin > TAU)) {                 // NaN margin also flags
        int pos = atomicAdd(ambigCount, 1);
        if (pos < N_PTS) ambigList[pos] = m0 + t;
      }
    }
  }
}

// Exact recheck of ambiguous points with the r5 bit-exact scheme.
__launch_bounds__(256)
__global__ void refine_kernel(const float* __restrict__ x,
                              const float* __restrict__ ctr,
                              const float* __restrict__ cnorm,
                              const int* __restrict__ ambigList,
                              const int* __restrict__ ambigCount,
                              int* __restrict__ assign) {
  __shared__ float xrow[DIM];
  __shared__ float cs[K_CL][33];
  __shared__ float rv[K_CL];
  __shared__ int   ri[K_CL];
  const int t = threadIdx.x;
  int cnt = *ambigCount; if (cnt > N_PTS) cnt = N_PTS;
  for (int a = blockIdx.x; a < cnt; a += gridDim.x) {
    int pt = ambigList[a];
    __syncthreads();
    for (int u = t; u < DIM; u += 256) xrow[u] = x[(size_t)pt * DIM + u];
    float accA = 0.f, accB = 0.f;
    for (int c = 0; c < 16; c++) {
      __syncthreads();
      for (int u = t; u < K_CL * 32; u += 256) {
        int k = u >> 5, j = u & 31;
        cs[k][j] = ctr[(size_t)k * DIM + c * 32 + j];
      }
      __syncthreads();
      {
#pragma clang fp contract(off)
        float s = (c < 9) ? accA : accB;
        for (int j = 0; j < 32; j++) {
          float pv = xrow[c * 32 + j] * cs[t][j];
          s = s + pv;
        }
        if (c < 9) accA = s; else accB = s;
      }
    }
    float d2;
    {
#pragma clang fp contract(off)
      float dot = accA + accB;
      float tw = 2.0f * dot;
      d2 = cnorm[t] - tw;
    }
    rv[t] = d2; ri[t] = t;
    __syncthreads();
    for (int st = 128; st >= 1; st >>= 1) {
      if (t < st) argmin_pick(rv[t + st], ri[t + st], rv[t], ri[t]);
      __syncthreads();
    }
    if (t == 0) assign[pt] = ri[0];
  }
}

// Counting sort stage 1: per-block histogram, BLOCK-major output (coalesced).
__global__ void hist_kernel(const int* __restrict__ assign, int* __restrict__ blockHist) {
  __shared__ int h[K_CL];
  int b = blockIdx.x, t = threadIdx.x;
  h[t] = 0; __syncthreads();
  int k = assign[b * 256 + t];
  atomicAdd(&h[k], 1);
  __syncthreads();
  blockHist[b * 256 + t] = h[t];
}

// Stage 2a: per-cluster exclusive scan over the 256 block values (parallel).
__global__ void scan_blocks_kernel(int* __restrict__ blockHist,
                                   int* __restrict__ counts) {
  __shared__ int v[256];
  int k = blockIdx.x, b = threadIdx.x;
  int x = blockHist[b * 256 + k];
  v[b] = x;
  __syncthreads();
  for (int s = 1; s < 256; s <<= 1) {
    int add = (b >= s) ? v[b - s] : 0;
    __syncthreads();
    v[b] += add;
    __syncthreads();
  }
  blockHist[b * 256 + k] = v[b] - x;
  if (b == 255) counts[k] = v[255];
}

// Stage 2b: exclusive scan of cluster totals -> clusterStart. One block.
__global__ void scan_clusters_kernel(const int* __restrict__ counts,
                                     int* __restrict__ clusterStart) {
  __shared__ int v[256];
  int k = threadIdx.x;
  int x = counts[k];
  v[k] = x;
  __syncthreads();
  for (int s = 1; s < 256; s <<= 1) {
    int add = (k >= s) ? v[k - s] : 0;
    __syncthreads();
    v[k] += add;
    __syncthreads();
  }
  clusterStart[k] = v[k] - x;
}

// Stage 3: stable scatter of point indices into cluster-sorted order.
__global__ void scatter_kernel(const int* __restrict__ assign,
                               const int* __restrict__ blockHist,
                               const int* __restrict__ clusterStart,
                               int* __restrict__ sortedIdx) {
  __shared__ int la[256];
  int b = blockIdx.x, t = threadIdx.x;
  int n = b * 256 + t;
  int k = assign[n];
  la[t] = k; __syncthreads();
  int rank = 0;
  for (int u = 0; u < t; u++) rank += (la[u] == k) ? 1 : 0;
  sortedIdx[clusterStart[k] + blockHist[b * 256 + k] + rank] = n;
}

// Stage 4a: per-(cluster, chunk) partial sums, nch chunks per cluster.
__global__ void segsum_part_kernel(const float* __restrict__ x,
                                   const int* __restrict__ sortedIdx,
                                   const int* __restrict__ clusterStart,
                                   const int* __restrict__ counts,
                                   float* __restrict__ part, int nch) {
#pragma clang fp contract(off)
  int k = blockIdx.x / nch;      // cluster
  int c = blockIdx.x - k * nch;  // chunk
  int d = threadIdx.x;
  int start = clusterStart[k], cnt = counts[k];
  int ch = (cnt + nch - 1) / nch;
  int b0 = c * ch;
  int b1 = b0 + ch; if (b1 > cnt) b1 = cnt;
  float s = 0.f;
  for (int i = b0; i < b1; i++) {
    int idx = sortedIdx[start + i];
    s = s + x[(size_t)idx * DIM + d];
  }
  part[((size_t)k * nch + c) * DIM + d] = s;
}

// Stage 4b (last iter): combine chunks ascending, divide -> out.
__global__ void segsum_final_kernel(const float* __restrict__ part,
                                    const int* __restrict__ counts,
                                    float* __restrict__ out, int nch) {
#pragma clang fp contract(off)
  int k = blockIdx.x, d = threadIdx.x;
  float s = 0.f;
  for (int c = 0; c < nch; c++)
    s = s + part[((size_t)k * nch + c) * DIM + d];
  out[k * DIM + d] = s / (float)counts[k];   // cnt==0 -> NaN, matches ref
}

// Stage 4b + prep fused (iters 0..ITERS-2): combine chunks -> next centers,
// split to bf16 planes, cnorm (same strict-sequential order), zero ambig.
__global__ void update_kernel(const float* __restrict__ part,
                              const int* __restrict__ counts,
                              float* __restrict__ ctrNext,
                              float* __restrict__ cnorm,
                              int* __restrict__ ambigCount,
                              ushort* __restrict__ ch,
                              ushort* __restrict__ cm, int nch) {
  __shared__ float row[DIM];
  const int k = blockIdx.x, t = threadIdx.x;   // 512 threads, t = dim
  {
#pragma clang fp contract(off)
    float s = 0.f;
    for (int c = 0; c < nch; c++)
      s = s + part[((size_t)k * nch + c) * DIM + t];
    float mean = s / (float)counts[k];         // cnt==0 -> NaN, matches ref
    ctrNext[(size_t)k * DIM + t] = mean;
    row[t] = mean;
  }
  {
    ushort h, m;
    split2(row[t], h, m);
    ch[(size_t)k * DIM + t] = h;
    cm[(size_t)k * DIM + t] = m;
  }
  __syncthreads();
  if (t == 0) {
#pragma clang fp contract(off)
    float s = 0.f;
    for (int j = 0; j < DIM; j++) {
      float v = row[j];
      float p = v * v;
      s = s + p;
    }
    cnorm[k] = s;
  }
  if (t == 1 && k == 0) *ambigCount = 0;
}

// ---------------- host ----------------
static inline void run_sort(unsigned long long* d, hipStream_t stream) {
  bitonic_local_start<<<32, 1024, 0, stream>>>(d);
  for (int k = 4096; k <= 65536; k <<= 1) {
    for (int j = k >> 1; j >= 2048; j >>= 1)
      bitonic_global_step<<<128, 256, 0, stream>>>(d, k, j);
    bitonic_local<<<32, 1024, 0, stream>>>(d, k);
  }
}

extern "C" void kernel_launch(void* const* d_in, const int* in_sizes, int n_in,
                              void* d_out, int out_size, void* d_ws, size_t ws_size,
                              hipStream_t stream) {
  const float* x = (const float*)d_in[0];
  float* out = (float*)d_out;

  char* p = (char*)d_ws;
  size_t used = 0;
  auto alloc = [&](size_t bytes) {
    char* r = p;
    size_t rb = (bytes + 255) & ~(size_t)255;
    p += rb; used += rb;
    return r;
  };
  unsigned long long* keyA = (unsigned long long*)alloc(N_PTS * 8);
  unsigned long long* keyB = (unsigned long long*)alloc(N_PTS * 8);
  uint32_t* perm1          = (uint32_t*)alloc(N_PTS * 4);
  int* assign              = (int*)alloc(N_PTS * 4);
  int* blockHist           = (int*)alloc(K_CL * 256 * 4);
  int* clusterStart        = (int*)alloc(K_CL * 4);
  int* counts              = (int*)alloc(K_CL * 4);
  int* sortedIdx           = (int*)alloc(N_PTS * 4);
  float* ctrA              = (float*)alloc(K_CL * DIM * 4);
  float* ctrB              = (float*)alloc(K_CL * DIM * 4);
  float* cnorm             = (float*)alloc(K_CL * 4);
  ushort* ch               = (ushort*)alloc((size_t)K_CL * DIM * 2);
  ushort* cm               = (ushort*)alloc((size_t)K_CL * DIM * 2);
  int* ambigCount          = (int*)alloc(4);
  int* ambigList           = (int*)alloc(N_PTS * 4);

  // Chunk count for segsum: 64 if workspace allows, else 8.
  const size_t part64 = (size_t)K_CL * 64 * DIM * 4;   // 33.5 MB
  int nch = (ws_size >= used + part64 + 256) ? 64 : 8;
  float* part = (float*)alloc((size_t)K_CL * nch * DIM * 4);

  // Partitionable (foldlike) threefry split: split(key)[j] = hash(key,(0,j)).
  uint32_t k1a, k1b, s1a, s1b;
  tf2x32(0u, 1u, 0u, 0u, &k1a, &k1b);
  tf2x32(0u, 1u, 0u, 1u, &s1a, &s1b);
  uint32_t k2a, k2b, s2a, s2b;
  tf2x32(k1a, k1b, 0u, 0u, &k2a, &k2b);
  tf2x32(k1a, k1b, 0u, 1u, &s2a, &s2b);

  genbits_kernel<<<256, 256, 0, stream>>>(keyA, s1a, s1b);
  run_sort(keyA, stream);
  extract_low_kernel<<<256, 256, 0, stream>>>(keyA, perm1);
  genbits_kernel<<<256, 256, 0, stream>>>(keyB, s2a, s2b);
  run_sort(keyB, stream);
  init_centers_kernel<<<K_CL, DIM, 0, stream>>>(keyB, perm1, x, ctrA);
  prep_kernel<<<K_CL, 256, 0, stream>>>(ctrA, cnorm, ambigCount, ch, cm);

  float* cur = ctrA;
  for (int it = 0; it < ITERS; ++it) {
    assign_mfma_kernel<<<N_PTS / BM, 256, 0, stream>>>(x, ch, cm, cnorm, assign,
                                                       ambigCount, ambigList);
    refine_kernel<<<256, 256, 0, stream>>>(x, cur, cnorm, ambigList, ambigCount, assign);
    hist_kernel<<<256, 256, 0, stream>>>(assign, blockHist);
    scan_blocks_kernel<<<256, 256, 0, stream>>>(blockHist, counts);
    scan_clusters_kernel<<<1, 256, 0, stream>>>(counts, clusterStart);
    scatter_kernel<<<256, 256, 0, stream>>>(assign, blockHist, clusterStart, sortedIdx);
    segsum_part_kernel<<<K_CL * nch, DIM, 0, stream>>>(x, sortedIdx, clusterStart,
                                                       counts, part, nch);
    if (it < ITERS - 1) {
      float* next = (it & 1) ? ctrA : ctrB;
      update_kernel<<<K_CL, DIM, 0, stream>>>(part, counts, next, cnorm,
                                              ambigCount, ch, cm, nch);
      cur = next;
    } else {
      segsum_final_kernel<<<K_CL, DIM, 0, stream>>>(part, counts, out, nch);
    }
  }
}

// Round 21
// 6477.052 us; speedup vs baseline: 1.1150x; 1.0065x over previous
//
#include <hip/hip_runtime.h>
#include <hip/hip_bf16.h>
#include <stdint.h>

#define N_PTS   65536
#define DIM     512
#define K_CL    256
#define ITERS   25
#define BM      64         // points per block in assign
#define TAU     1e-2f      // ambiguity margin; fast-path err max ~1e-3 << TAU/2

typedef __attribute__((ext_vector_type(8))) short  bf16x8;   // 8 bf16 (4 VGPRs)
typedef __attribute__((ext_vector_type(4))) float  f32x4;

// ---------------- Threefry-2x32 (JAX-exact, 20 rounds) ----------------
__host__ __device__ static inline uint32_t rotl32(uint32_t x, int d) {
  return (x << d) | (x >> (32 - d));
}

__host__ __device__ static inline void tf2x32(uint32_t k0, uint32_t k1,
                                              uint32_t x0, uint32_t x1,
                                              uint32_t* o0, uint32_t* o1) {
  const uint32_t ks0 = k0, ks1 = k1, ks2 = k0 ^ k1 ^ 0x1BD11BDAu;
  uint32_t v0 = x0 + ks0, v1 = x1 + ks1;
#define TF_ROUND(R) { v0 += v1; v1 = rotl32(v1, R); v1 ^= v0; }
  TF_ROUND(13) TF_ROUND(15) TF_ROUND(26) TF_ROUND(6)
  v0 += ks1; v1 += ks2 + 1u;
  TF_ROUND(17) TF_ROUND(29) TF_ROUND(16) TF_ROUND(24)
  v0 += ks2; v1 += ks0 + 2u;
  TF_ROUND(13) TF_ROUND(15) TF_ROUND(26) TF_ROUND(6)
  v0 += ks0; v1 += ks1 + 3u;
  TF_ROUND(17) TF_ROUND(29) TF_ROUND(16) TF_ROUND(24)
  v0 += ks1; v1 += ks2 + 4u;
  TF_ROUND(13) TF_ROUND(15) TF_ROUND(26) TF_ROUND(6)
  v0 += ks2; v1 += ks0 + 5u;
#undef TF_ROUND
  *o0 = v0; *o1 = v1;
}

// Partitionable random_bits (32-bit): bits[i] = y0 ^ y1 of hash(key,(0,i)).
__global__ void genbits_kernel(unsigned long long* __restrict__ keyarr,
                               uint32_t k0, uint32_t k1) {
  int i = blockIdx.x * 256 + threadIdx.x;
  uint32_t y0, y1;
  tf2x32(k0, k1, 0u, (uint32_t)i, &y0, &y1);
  uint32_t bits = y0 ^ y1;
  keyarr[i] = ((unsigned long long)bits << 32) | (uint32_t)i;
}

// ---- Bitonic sort, identical comparison network, split across launches ----
__global__ void bitonic_global_step(unsigned long long* __restrict__ d,
                                    int k, int j) {
  int t = blockIdx.x * 256 + threadIdx.x;   // 0..32767
  int low = t & (j - 1);
  int i   = ((t ^ low) << 1) | low;
  int ixj = i | j;
  bool up = ((i & k) == 0);
  unsigned long long a = d[i], b = d[ixj];
  if ((a > b) == up) { d[i] = b; d[ixj] = a; }
}

__global__ void bitonic_local_start(unsigned long long* __restrict__ d) {
  __shared__ unsigned long long s[2048];
  const int base = blockIdx.x * 2048;
  for (int u = threadIdx.x; u < 2048; u += 1024) s[u] = d[base + u];
  __syncthreads();
  for (int k = 2; k <= 2048; k <<= 1) {
    for (int j = k >> 1; j > 0; j >>= 1) {
      int t = threadIdx.x;
      int low = t & (j - 1);
      int il  = ((t ^ low) << 1) | low;
      int ixj = il | j;
      bool up = (((base + il) & k) == 0);
      unsigned long long a = s[il], b = s[ixj];
      if ((a > b) == up) { s[il] = b; s[ixj] = a; }
      __syncthreads();
    }
  }
  for (int u = threadIdx.x; u < 2048; u += 1024) d[base + u] = s[u];
}

__global__ void bitonic_local(unsigned long long* __restrict__ d, int k) {
  __shared__ unsigned long long s[2048];
  const int base = blockIdx.x * 2048;
  for (int u = threadIdx.x; u < 2048; u += 1024) s[u] = d[base + u];
  __syncthreads();
  for (int j = 1024; j > 0; j >>= 1) {
    int t = threadIdx.x;
    int low = t & (j - 1);
    int il  = ((t ^ low) << 1) | low;
    int ixj = il | j;
    bool up = (((base + il) & k) == 0);
    unsigned long long a = s[il], b = s[ixj];
    if ((a > b) == up) { s[il] = b; s[ixj] = a; }
    __syncthreads();
  }
  for (int u = threadIdx.x; u < 2048; u += 1024) d[base + u] = s[u];
}

__global__ void extract_low_kernel(const unsigned long long* __restrict__ s,
                                   uint32_t* __restrict__ out) {
  int i = blockIdx.x * 256 + threadIdx.x;
  out[i] = (uint32_t)(s[i] & 0xffffffffULL);
}

__global__ void init_centers_kernel(const unsigned long long* __restrict__ sorted2,
                                    const uint32_t* __restrict__ perm1,
                                    const float* __restrict__ x,
                                    float* __restrict__ ctr) {
  int k = blockIdx.x, d = threadIdx.x;
  uint32_t p   = (uint32_t)(sorted2[k] & 0xffffffffULL);
  uint32_t src = perm1[p];
  ctr[k * DIM + d] = x[(size_t)src * DIM + d];
}

// ---------------- bf16 2-way split helpers ----------------
__device__ static inline ushort f2bf(float f) {
  __hip_bfloat16 b = __float2bfloat16(f);
  return *reinterpret_cast<ushort*>(&b);
}
__device__ static inline float bf2f(ushort u) {
  __hip_bfloat16 b = *reinterpret_cast<__hip_bfloat16*>(&u);
  return __bfloat162float(b);
}
__device__ static inline void split2(float v, ushort& h, ushort& m) {
#pragma clang fp contract(off)
  h = f2bf(v);
  float r1 = v - bf2f(h);
  m = f2bf(r1);
}

// ---------------- iteration-0 prep (cnorm + csplit + zero) ----------------
__global__ void prep_kernel(const float* __restrict__ ctr,
                            float* __restrict__ cnorm,
                            int* __restrict__ ambigCount,
                            ushort* __restrict__ ch,
                            ushort* __restrict__ cm) {
  __shared__ float row[DIM];
  const int k = blockIdx.x, t = threadIdx.x;
  if (k == 0 && t == 0) *ambigCount = 0;
  row[t]       = ctr[(size_t)k * DIM + t];
  row[t + 256] = ctr[(size_t)k * DIM + t + 256];
  __syncthreads();
#pragma unroll
  for (int u = t; u < DIM; u += 256) {
    ushort h, m;
    split2(row[u], h, m);
    ch[(size_t)k * DIM + u] = h;
    cm[(size_t)k * DIM + u] = m;
  }
  if (t == 0) {
#pragma clang fp contract(off)
    float s = 0.f;
    for (int j = 0; j < DIM; j++) {
      float v = row[j];
      float p = v * v;
      s = s + p;
    }
    cnorm[k] = s;
  }
}

// argmin fold: NaN is minimal; first index wins ties (lexicographic).
__device__ static inline void argmin_pick(float ov, int ok, float& bv, int& bk) {
  bool no = __builtin_isnan(ov), nb = __builtin_isnan(bv);
  bool take;
  if (no != nb)      take = no;
  else if (no)       take = ok < bk;
  else               take = (ov < bv) || (ov == bv && ok < bk);
  if (take) { bv = ov; bk = ok; }
}

// ---- (best, idx, second) triple machinery for margin tracking ----
__device__ static inline bool before3(float a, int ai, float b, int bi) {
  bool na = __builtin_isnan(a), nb = __builtin_isnan(b);
  if (na != nb) return na;
  if (na)       return ai < bi;
  return a < b || (a == b && ai < bi);
}
__device__ static inline float valmin3(float a, float b) {
  if (__builtin_isnan(a) || __builtin_isnan(b)) return __int_as_float(0x7fc00000);
  return fminf(a, b);
}
__device__ static inline void merge3(float ob, int oi, float os,
                                     float& b, int& i, float& s) {
  if (before3(ob, oi, b, i)) { s = valmin3(b, os); b = ob; i = oi; }
  else                        s = valmin3(s, ob);
}

// MFMA distance-GEMM + argmin + margin gate (r20 frozen).
#define LOAD_B(BH, BM, K0) {                                               \
  size_t rowoff_ = (size_t)(colbase + l15) * DIM + (K0) + l4 * 8;          \
  _Pragma("unroll")                                                        \
  for (int j_ = 0; j_ < 4; j_++) {                                         \
    size_t off_ = rowoff_ + (size_t)j_ * 16 * DIM;                         \
    BH[j_] = *reinterpret_cast<const bf16x8*>(&ch[off_]);                  \
    BM[j_] = *reinterpret_cast<const bf16x8*>(&cm[off_]);                  \
  } }

#define PREFETCH_A(K0) {                                                   \
  v0 = *reinterpret_cast<const float4*>(srcbase + (K0));                   \
  v1 = *reinterpret_cast<const float4*>(srcbase + (K0) + 4); }

#define WRITE_A(BUF) {                                                     \
  float vv_[8] = {v0.x, v0.y, v0.z, v0.w, v1.x, v1.y, v1.z, v1.w};         \
  bf16x8 vh_, vm_;                                                         \
  _Pragma("unroll")                                                        \
  for (int q_ = 0; q_ < 8; q_++) {                                         \
    ushort h_, m_;                                                         \
    split2(vv_[q_], h_, m_);                                               \
    vh_[q_] = (short)h_; vm_[q_] = (short)m_;                              \
  }                                                                        \
  *reinterpret_cast<bf16x8*>(&ah[BUF][sr][sko]) = vh_;                     \
  *reinterpret_cast<bf16x8*>(&am[BUF][sr][sko]) = vm_; }

#define MFMA_STEP(BUF, BH, BM)                                             \
  _Pragma("unroll")                                                        \
  for (int i_ = 0; i_ < 4; i_++) {                                         \
    int r_ = i_ * 16 + l15, ko_ = l4 * 8;                                  \
    bf16x8 fah_ = *reinterpret_cast<bf16x8*>(&ah[BUF][r_][ko_]);           \
    bf16x8 fam_ = *reinterpret_cast<bf16x8*>(&am[BUF][r_][ko_]);           \
    _Pragma("unroll")                                                      \
    for (int j_ = 0; j_ < 4; j_++) {                                       \
      acc[i_][j_] = __builtin_amdgcn_mfma_f32_16x16x32_bf16(fah_, BH[j_], acc[i_][j_], 0, 0, 0); \
      acc[i_][j_] = __builtin_amdgcn_mfma_f32_16x16x32_bf16(fah_, BM[j_], acc[i_][j_], 0, 0, 0); \
      acc[i_][j_] = __builtin_amdgcn_mfma_f32_16x16x32_bf16(fam_, BH[j_], acc[i_][j_], 0, 0, 0); \
    } }

#define LDS_BARRIER() do {                                                 \
  asm volatile("s_waitcnt lgkmcnt(0)" ::: "memory");                       \
  __builtin_amdgcn_s_barrier();                                            \
} while (0)

__launch_bounds__(256, 4)
__global__ void assign_mfma_kernel(const float* __restrict__ x,
                                   const ushort* __restrict__ ch,
                                   const ushort* __restrict__ cm,
                                   const float* __restrict__ cnorm,
                                   int* __restrict__ assign,
                                   int* __restrict__ ambigCount,
                                   int* __restrict__ ambigList) {
  __shared__ __align__(16) ushort ah[2][64][40], am[2][64][40];   // 20.5 KB
  __shared__ float  redv[4][64];
  __shared__ int    redi[4][64];
  __shared__ float  reds[4][64];

  const int t = threadIdx.x;
  const int w = t >> 6;
  const int lane = t & 63;
  const int m0 = blockIdx.x * BM;
  const int colbase = w * 64;
  const int l15 = lane & 15, l4 = lane >> 4;
  const int sr = t >> 2, sko = (t & 3) * 8;        // staging map
  const float* srcbase = &x[(size_t)(m0 + sr) * DIM + sko];

  f32x4 acc[4][4];
#pragma unroll
  for (int i = 0; i < 4; i++)
#pragma unroll
    for (int j = 0; j < 4; j++) acc[i][j] = (f32x4)(0.f);

  bf16x8 bhA[4], bmA[4], bhB[4], bmB[4];
  float4 v0, v1;

  // prologue: stage A(k=0) into buf 0; load B(k=0) into set A
  PREFETCH_A(0);
  WRITE_A(0);
  LOAD_B(bhA, bmA, 0);
  __syncthreads();

#pragma unroll
  for (int ks2 = 0; ks2 < 16; ks2 += 2) {
    const int k0 = ks2 * 32;
    // ---- even step (ks = ks2): A in buf0, B in set A ----
    PREFETCH_A(k0 + 32);                 // A for ks2+1 (always exists)
    LOAD_B(bhB, bmB, k0 + 32);           // B for ks2+1, issued BEFORE MFMAs
    MFMA_STEP(0, bhA, bmA);
    WRITE_A(1);
    LDS_BARRIER();                       // vmcnt stays in flight
    // ---- odd step (ks = ks2+1): A in buf1, B in set B ----
    if (ks2 + 2 < 16) {
      PREFETCH_A(k0 + 64);
      LOAD_B(bhA, bmA, k0 + 64);
    }
    MFMA_STEP(1, bhB, bmB);
    if (ks2 + 2 < 16) WRITE_A(0);
    LDS_BARRIER();
  }

  // ---- epilogue: d2 = cnorm - 2*dot; (best, idx, second); margin gate ----
  {
#pragma clang fp contract(off)
    float cn[4];
#pragma unroll
    for (int j = 0; j < 4; j++) cn[j] = cnorm[colbase + j * 16 + l15];

#pragma unroll
    for (int i = 0; i < 4; i++) {
#pragma unroll
      for (int reg = 0; reg < 4; reg++) {
        float bb = __int_as_float(0x7f800000);  // +inf
        int   bi = 0x7fffffff;
        float bs = __int_as_float(0x7f800000);
#pragma unroll
        for (int j = 0; j < 4; j++) {
          int col = colbase + j * 16 + l15;
          float d2 = cn[j] - 2.0f * acc[i][j][reg];
          merge3(d2, col, __int_as_float(0x7f800000), bb, bi, bs);
        }
#pragma unroll
        for (int s = 1; s < 16; s <<= 1) {
          float ob = __shfl_xor(bb, s);
          int   oi = __shfl_xor(bi, s);
          float os = __shfl_xor(bs, s);
          merge3(ob, oi, os, bb, bi, bs);
        }
        if (l15 == 0) {
          int row = i * 16 + l4 * 4 + reg;
          redv[w][row] = bb; redi[w][row] = bi; reds[w][row] = bs;
        }
      }
    }
    __syncthreads();
    if (t < 64) {
      float bb = __int_as_float(0x7f800000);
      int   bi = 0x7fffffff;
      float bs = __int_as_float(0x7f800000);
#pragma unroll
      for (int w2 = 0; w2 < 4; w2++)
        merge3(redv[w2][t], redi[w2][t], reds[w2][t], bb, bi, bs);
      assign[m0 + t] = bi;
      float margin = bs - bb;
      if (!(margin > TAU)) {                 // NaN margin also flags
        int pos = atomicAdd(ambigCount, 1);
        if (pos < N_PTS) ambigList[pos] = m0 + t;
      }
    }
  }
}

// Exact recheck of ambiguous points with the r5 bit-exact scheme.
__launch_bounds__(256)
__global__ void refine_kernel(const float* __restrict__ x,
                              const float* __restrict__ ctr,
                              const float* __restrict__ cnorm,
                              const int* __restrict__ ambigList,
                              const int* __restrict__ ambigCount,
                              int* __restrict__ assign) {
  __shared__ float xrow[DIM];
  __shared__ float cs[K_CL][33];
  __shared__ float rv[K_CL];
  __shared__ int   ri[K_CL];
  const int t = threadIdx.x;
  int cnt = *ambigCount; if (cnt > N_PTS) cnt = N_PTS;
  for (int a = blockIdx.x; a < cnt; a += gridDim.x) {
    int pt = ambigList[a];
    __syncthreads();
    for (int u = t; u < DIM; u += 256) xrow[u] = x[(size_t)pt * DIM + u];
    float accA = 0.f, accB = 0.f;
    for (int c = 0; c < 16; c++) {
      __syncthreads();
      for (int u = t; u < K_CL * 32; u += 256) {
        int k = u >> 5, j = u & 31;
        cs[k][j] = ctr[(size_t)k * DIM + c * 32 + j];
      }
      __syncthreads();
      {
#pragma clang fp contract(off)
        float s = (c < 9) ? accA : accB;
        for (int j = 0; j < 32; j++) {
          float pv = xrow[c * 32 + j] * cs[t][j];
          s = s + pv;
        }
        if (c < 9) accA = s; else accB = s;
      }
    }
    float d2;
    {
#pragma clang fp contract(off)
      float dot = accA + accB;
      float tw = 2.0f * dot;
      d2 = cnorm[t] - tw;
    }
    rv[t] = d2; ri[t] = t;
    __syncthreads();
    for (int st = 128; st >= 1; st >>= 1) {
      if (t < st) argmin_pick(rv[t + st], ri[t + st], rv[t], ri[t]);
      __syncthreads();
    }
    if (t == 0) assign[pt] = ri[0];
  }
}

// Counting sort stage 1: per-block histogram, BLOCK-major output (coalesced).
__global__ void hist_kernel(const int* __restrict__ assign, int* __restrict__ blockHist) {
  __shared__ int h[K_CL];
  int b = blockIdx.x, t = threadIdx.x;
  h[t] = 0; __syncthreads();
  int k = assign[b * 256 + t];
  atomicAdd(&h[k], 1);
  __syncthreads();
  blockHist[b * 256 + t] = h[t];
}

// Stage 2a: per-cluster exclusive scan over the 256 block values (parallel).
__global__ void scan_blocks_kernel(int* __restrict__ blockHist,
                                   int* __restrict__ counts) {
  __shared__ int v[256];
  int k = blockIdx.x, b = threadIdx.x;
  int x = blockHist[b * 256 + k];
  v[b] = x;
  __syncthreads();
  for (int s = 1; s < 256; s <<= 1) {
    int add = (b >= s) ? v[b - s] : 0;
    __syncthreads();
    v[b] += add;
    __syncthreads();
  }
  blockHist[b * 256 + k] = v[b] - x;
  if (b == 255) counts[k] = v[255];
}

// Stage 2b: exclusive scan of cluster totals -> clusterStart. One block.
__global__ void scan_clusters_kernel(const int* __restrict__ counts,
                                     int* __restrict__ clusterStart) {
  __shared__ int v[256];
  int k = threadIdx.x;
  int x = counts[k];
  v[k] = x;
  __syncthreads();
  for (int s = 1; s < 256; s <<= 1) {
    int add = (k >= s) ? v[k - s] : 0;
    __syncthreads();
    v[k] += add;
    __syncthreads();
  }
  clusterStart[k] = v[k] - x;
}

// Stage 3: stable scatter via ballot ranking.  rank(t) = #{u<t : key[u]==k}
// computed as (earlier waves' per-key counts) + (same-key lanes below me).
// Deterministic; identical sortedIdx to the serial-rank version.
__global__ void scatter_kernel(const int* __restrict__ assign,
                               const int* __restrict__ blockHist,
                               const int* __restrict__ clusterStart,
                               int* __restrict__ sortedIdx) {
  __shared__ int whist[4][K_CL];               // per-wave key counts
  int b = blockIdx.x, t = threadIdx.x;
  int w = t >> 6, lane = t & 63;
  int n = b * 256 + t;
  int k = assign[n];
  for (int u = t; u < 4 * K_CL; u += 256) (&whist[0][0])[u] = 0;
  __syncthreads();
  // same-key mask within this wave: 8 ballots over the key bits
  unsigned long long same = ~0ULL;
#pragma unroll
  for (int bit = 0; bit < 8; bit++) {
    unsigned long long m = __ballot((k >> bit) & 1);
    same &= ((k >> bit) & 1) ? m : ~m;
  }
  unsigned long long below = same & ((lane == 0) ? 0ULL : ((~0ULL) >> (64 - lane)));
  int rank_in_wave = __popcll(below);
  if (rank_in_wave == 0) whist[w][k] = __popcll(same);   // one writer per key
  __syncthreads();
  int rank = rank_in_wave;
  for (int w2 = 0; w2 < w; w2++) rank += whist[w2][k];
  sortedIdx[clusterStart[k] + blockHist[b * 256 + k] + rank] = n;
}

// Stage 4a: per-(cluster, chunk) partial sums, nch chunks per cluster.
__global__ void segsum_part_kernel(const float* __restrict__ x,
                                   const int* __restrict__ sortedIdx,
                                   const int* __restrict__ clusterStart,
                                   const int* __restrict__ counts,
                                   float* __restrict__ part, int nch) {
#pragma clang fp contract(off)
  int k = blockIdx.x / nch;      // cluster
  int c = blockIdx.x - k * nch;  // chunk
  int d = threadIdx.x;
  int start = clusterStart[k], cnt = counts[k];
  int ch = (cnt + nch - 1) / nch;
  int b0 = c * ch;
  int b1 = b0 + ch; if (b1 > cnt) b1 = cnt;
  float s = 0.f;
  for (int i = b0; i < b1; i++) {
    int idx = sortedIdx[start + i];
    s = s + x[(size_t)idx * DIM + d];
  }
  part[((size_t)k * nch + c) * DIM + d] = s;
}

// Stage 4b (last iter): combine chunks ascending, divide -> out.
__global__ void segsum_final_kernel(const float* __restrict__ part,
                                    const int* __restrict__ counts,
                                    float* __restrict__ out, int nch) {
#pragma clang fp contract(off)
  int k = blockIdx.x, d = threadIdx.x;
  float s = 0.f;
  for (int c = 0; c < nch; c++)
    s = s + part[((size_t)k * nch + c) * DIM + d];
  out[k * DIM + d] = s / (float)counts[k];   // cnt==0 -> NaN, matches ref
}

// Stage 4b + prep fused (iters 0..ITERS-2): combine chunks -> next centers,
// split to bf16 planes, cnorm (same strict-sequential order), zero ambig.
__global__ void update_kernel(const float* __restrict__ part,
                              const int* __restrict__ counts,
                              float* __restrict__ ctrNext,
                              float* __restrict__ cnorm,
                              int* __restrict__ ambigCount,
                              ushort* __restrict__ ch,
                              ushort* __restrict__ cm, int nch) {
  __shared__ float row[DIM];
  const int k = blockIdx.x, t = threadIdx.x;   // 512 threads, t = dim
  {
#pragma clang fp contract(off)
    float s = 0.f;
    for (int c = 0; c < nch; c++)
      s = s + part[((size_t)k * nch + c) * DIM + t];
    float mean = s / (float)counts[k];         // cnt==0 -> NaN, matches ref
    ctrNext[(size_t)k * DIM + t] = mean;
    row[t] = mean;
  }
  {
    ushort h, m;
    split2(row[t], h, m);
    ch[(size_t)k * DIM + t] = h;
    cm[(size_t)k * DIM + t] = m;
  }
  __syncthreads();
  if (t == 0) {
#pragma clang fp contract(off)
    float s = 0.f;
    for (int j = 0; j < DIM; j++) {
      float v = row[j];
      float p = v * v;
      s = s + p;
    }
    cnorm[k] = s;
  }
  if (t == 1 && k == 0) *ambigCount = 0;
}

// ---------------- host ----------------
static inline void run_sort(unsigned long long* d, hipStream_t stream) {
  bitonic_local_start<<<32, 1024, 0, stream>>>(d);
  for (int k = 4096; k <= 65536; k <<= 1) {
    for (int j = k >> 1; j >= 2048; j >>= 1)
      bitonic_global_step<<<128, 256, 0, stream>>>(d, k, j);
    bitonic_local<<<32, 1024, 0, stream>>>(d, k);
  }
}

extern "C" void kernel_launch(void* const* d_in, const int* in_sizes, int n_in,
                              void* d_out, int out_size, void* d_ws, size_t ws_size,
                              hipStream_t stream) {
  const float* x = (const float*)d_in[0];
  float* out = (float*)d_out;

  char* p = (char*)d_ws;
  size_t used = 0;
  auto alloc = [&](size_t bytes) {
    char* r = p;
    size_t rb = (bytes + 255) & ~(size_t)255;
    p += rb; used += rb;
    return r;
  };
  unsigned long long* keyA = (unsigned long long*)alloc(N_PTS * 8);
  unsigned long long* keyB = (unsigned long long*)alloc(N_PTS * 8);
  uint32_t* perm1          = (uint32_t*)alloc(N_PTS * 4);
  int* assign              = (int*)alloc(N_PTS * 4);
  int* blockHist           = (int*)alloc(K_CL * 256 * 4);
  int* clusterStart        = (int*)alloc(K_CL * 4);
  int* counts              = (int*)alloc(K_CL * 4);
  int* sortedIdx           = (int*)alloc(N_PTS * 4);
  float* ctrA              = (float*)alloc(K_CL * DIM * 4);
  float* ctrB              = (float*)alloc(K_CL * DIM * 4);
  float* cnorm             = (float*)alloc(K_CL * 4);
  ushort* ch               = (ushort*)alloc((size_t)K_CL * DIM * 2);
  ushort* cm               = (ushort*)alloc((size_t)K_CL * DIM * 2);
  int* ambigCount          = (int*)alloc(4);
  int* ambigList           = (int*)alloc(N_PTS * 4);

  // Chunk count for segsum: 64 if workspace allows, else 8.
  const size_t part64 = (size_t)K_CL * 64 * DIM * 4;   // 33.5 MB
  int nch = (ws_size >= used + part64 + 256) ? 64 : 8;
  float* part = (float*)alloc((size_t)K_CL * nch * DIM * 4);

  // Partitionable (foldlike) threefry split: split(key)[j] = hash(key,(0,j)).
  uint32_t k1a, k1b, s1a, s1b;
  tf2x32(0u, 1u, 0u, 0u, &k1a, &k1b);
  tf2x32(0u, 1u, 0u, 1u, &s1a, &s1b);
  uint32_t k2a, k2b, s2a, s2b;
  tf2x32(k1a, k1b, 0u, 0u, &k2a, &k2b);
  tf2x32(k1a, k1b, 0u, 1u, &s2a, &s2b);

  genbits_kernel<<<256, 256, 0, stream>>>(keyA, s1a, s1b);
  run_sort(keyA, stream);
  extract_low_kernel<<<256, 256, 0, stream>>>(keyA, perm1);
  genbits_kernel<<<256, 256, 0, stream>>>(keyB, s2a, s2b);
  run_sort(keyB, stream);
  init_centers_kernel<<<K_CL, DIM, 0, stream>>>(keyB, perm1, x, ctrA);
  prep_kernel<<<K_CL, 256, 0, stream>>>(ctrA, cnorm, ambigCount, ch, cm);

  float* cur = ctrA;
  for (int it = 0; it < ITERS; ++it) {
    assign_mfma_kernel<<<N_PTS / BM, 256, 0, stream>>>(x, ch, cm, cnorm, assign,
                                                       ambigCount, ambigList);
    refine_kernel<<<256, 256, 0, stream>>>(x, cur, cnorm, ambigList, ambigCount, assign);
    hist_kernel<<<256, 256, 0, stream>>>(assign, blockHist);
    scan_blocks_kernel<<<256, 256, 0, stream>>>(blockHist, counts);
    scan_clusters_kernel<<<1, 256, 0, stream>>>(counts, clusterStart);
    scatter_kernel<<<256, 256, 0, stream>>>(assign, blockHist, clusterStart, sortedIdx);
    segsum_part_kernel<<<K_CL * nch, DIM, 0, stream>>>(x, sortedIdx, clusterStart,
                                                       counts, part, nch);
    if (it < ITERS - 1) {
      float* next = (it & 1) ? ctrA : ctrB;
      update_kernel<<<K_CL, DIM, 0, stream>>>(part, counts, next, cnorm,
                                              ambigCount, ch, cm, nch);
      cur = next;
    } else {
      segsum_final_kernel<<<K_CL, DIM, 0, stream>>>(part, counts, out, nch);
    }
  }
}

// Round 22
// 6409.529 us; speedup vs baseline: 1.1268x; 1.0105x over previous
//
#include <hip/hip_runtime.h>
#include <hip/hip_bf16.h>
#include <stdint.h>

#define N_PTS   65536
#define DIM     512
#define K_CL    256
#define ITERS   25
#define BM      64         // points per block in assign
#define TAU     1e-2f      // ambiguity margin; fast-path err max ~1e-3 << TAU/2

typedef __attribute__((ext_vector_type(8))) short  bf16x8;   // 8 bf16 (4 VGPRs)
typedef __attribute__((ext_vector_type(4))) float  f32x4;

// ---------------- Threefry-2x32 (JAX-exact, 20 rounds) ----------------
__host__ __device__ static inline uint32_t rotl32(uint32_t x, int d) {
  return (x << d) | (x >> (32 - d));
}

__host__ __device__ static inline void tf2x32(uint32_t k0, uint32_t k1,
                                              uint32_t x0, uint32_t x1,
                                              uint32_t* o0, uint32_t* o1) {
  const uint32_t ks0 = k0, ks1 = k1, ks2 = k0 ^ k1 ^ 0x1BD11BDAu;
  uint32_t v0 = x0 + ks0, v1 = x1 + ks1;
#define TF_ROUND(R) { v0 += v1; v1 = rotl32(v1, R); v1 ^= v0; }
  TF_ROUND(13) TF_ROUND(15) TF_ROUND(26) TF_ROUND(6)
  v0 += ks1; v1 += ks2 + 1u;
  TF_ROUND(17) TF_ROUND(29) TF_ROUND(16) TF_ROUND(24)
  v0 += ks2; v1 += ks0 + 2u;
  TF_ROUND(13) TF_ROUND(15) TF_ROUND(26) TF_ROUND(6)
  v0 += ks0; v1 += ks1 + 3u;
  TF_ROUND(17) TF_ROUND(29) TF_ROUND(16) TF_ROUND(24)
  v0 += ks1; v1 += ks2 + 4u;
  TF_ROUND(13) TF_ROUND(15) TF_ROUND(26) TF_ROUND(6)
  v0 += ks2; v1 += ks0 + 5u;
#undef TF_ROUND
  *o0 = v0; *o1 = v1;
}

// Partitionable random_bits for BOTH arrays in one launch (512 blocks).
__global__ void genbits2_kernel(unsigned long long* __restrict__ keyA,
                                unsigned long long* __restrict__ keyB,
                                uint32_t a0, uint32_t a1,
                                uint32_t b0, uint32_t b1) {
  int g = blockIdx.x * 256 + threadIdx.x;
  if (g < N_PTS) {
    uint32_t y0, y1;
    tf2x32(a0, a1, 0u, (uint32_t)g, &y0, &y1);
    keyA[g] = ((unsigned long long)(y0 ^ y1) << 32) | (uint32_t)g;
  } else {
    int i = g - N_PTS;
    uint32_t y0, y1;
    tf2x32(b0, b1, 0u, (uint32_t)i, &y0, &y1);
    keyB[i] = ((unsigned long long)(y0 ^ y1) << 32) | (uint32_t)i;
  }
}

// ---- Bitonic sort over BOTH arrays (independent, identical network) ----
__global__ void bitonic_global_step2(unsigned long long* __restrict__ dA,
                                     unsigned long long* __restrict__ dB,
                                     int k, int j) {
  int g = blockIdx.x;                       // 0..255
  unsigned long long* d = (g < 128) ? dA : dB;
  int t = (g & 127) * 256 + threadIdx.x;    // 0..32767
  int low = t & (j - 1);
  int i   = ((t ^ low) << 1) | low;
  int ixj = i | j;
  bool up = ((i & k) == 0);
  unsigned long long a = d[i], b = d[ixj];
  if ((a > b) == up) { d[i] = b; d[ixj] = a; }
}

__global__ void bitonic_local_start2(unsigned long long* __restrict__ dA,
                                     unsigned long long* __restrict__ dB) {
  __shared__ unsigned long long s[2048];
  unsigned long long* d = (blockIdx.x < 32) ? dA : dB;
  const int base = (blockIdx.x & 31) * 2048;
  for (int u = threadIdx.x; u < 2048; u += 1024) s[u] = d[base + u];
  __syncthreads();
  for (int k = 2; k <= 2048; k <<= 1) {
    for (int j = k >> 1; j > 0; j >>= 1) {
      int t = threadIdx.x;
      int low = t & (j - 1);
      int il  = ((t ^ low) << 1) | low;
      int ixj = il | j;
      bool up = (((base + il) & k) == 0);
      unsigned long long a = s[il], b = s[ixj];
      if ((a > b) == up) { s[il] = b; s[ixj] = a; }
      __syncthreads();
    }
  }
  for (int u = threadIdx.x; u < 2048; u += 1024) d[base + u] = s[u];
}

__global__ void bitonic_local2(unsigned long long* __restrict__ dA,
                               unsigned long long* __restrict__ dB, int k) {
  __shared__ unsigned long long s[2048];
  unsigned long long* d = (blockIdx.x < 32) ? dA : dB;
  const int base = (blockIdx.x & 31) * 2048;
  for (int u = threadIdx.x; u < 2048; u += 1024) s[u] = d[base + u];
  __syncthreads();
  for (int j = 1024; j > 0; j >>= 1) {
    int t = threadIdx.x;
    int low = t & (j - 1);
    int il  = ((t ^ low) << 1) | low;
    int ixj = il | j;
    bool up = (((base + il) & k) == 0);
    unsigned long long a = s[il], b = s[ixj];
    if ((a > b) == up) { s[il] = b; s[ixj] = a; }
    __syncthreads();
  }
  for (int u = threadIdx.x; u < 2048; u += 1024) d[base + u] = s[u];
}

__global__ void extract_low_kernel(const unsigned long long* __restrict__ s,
                                   uint32_t* __restrict__ out) {
  int i = blockIdx.x * 256 + threadIdx.x;
  out[i] = (uint32_t)(s[i] & 0xffffffffULL);
}

__global__ void init_centers_kernel(const unsigned long long* __restrict__ sorted2,
                                    const uint32_t* __restrict__ perm1,
                                    const float* __restrict__ x,
                                    float* __restrict__ ctr) {
  int k = blockIdx.x, d = threadIdx.x;
  uint32_t p   = (uint32_t)(sorted2[k] & 0xffffffffULL);
  uint32_t src = perm1[p];
  ctr[k * DIM + d] = x[(size_t)src * DIM + d];
}

// ---------------- bf16 2-way split helpers ----------------
__device__ static inline ushort f2bf(float f) {
  __hip_bfloat16 b = __float2bfloat16(f);
  return *reinterpret_cast<ushort*>(&b);
}
__device__ static inline float bf2f(ushort u) {
  __hip_bfloat16 b = *reinterpret_cast<__hip_bfloat16*>(&u);
  return __bfloat162float(b);
}
__device__ static inline void split2(float v, ushort& h, ushort& m) {
#pragma clang fp contract(off)
  h = f2bf(v);
  float r1 = v - bf2f(h);
  m = f2bf(r1);
}

// ---------------- iteration-0 prep (cnorm + csplit + zero) ----------------
__global__ void prep_kernel(const float* __restrict__ ctr,
                            float* __restrict__ cnorm,
                            int* __restrict__ ambigCount,
                            ushort* __restrict__ ch,
                            ushort* __restrict__ cm) {
  __shared__ float row[DIM];
  const int k = blockIdx.x, t = threadIdx.x;
  if (k == 0 && t == 0) *ambigCount = 0;
  row[t]       = ctr[(size_t)k * DIM + t];
  row[t + 256] = ctr[(size_t)k * DIM + t + 256];
  __syncthreads();
#pragma unroll
  for (int u = t; u < DIM; u += 256) {
    ushort h, m;
    split2(row[u], h, m);
    ch[(size_t)k * DIM + u] = h;
    cm[(size_t)k * DIM + u] = m;
  }
  if (t == 0) {
#pragma clang fp contract(off)
    float s = 0.f;
    for (int j = 0; j < DIM; j++) {
      float v = row[j];
      float p = v * v;
      s = s + p;
    }
    cnorm[k] = s;
  }
}

// argmin fold: NaN is minimal; first index wins ties (lexicographic).
__device__ static inline void argmin_pick(float ov, int ok, float& bv, int& bk) {
  bool no = __builtin_isnan(ov), nb = __builtin_isnan(bv);
  bool take;
  if (no != nb)      take = no;
  else if (no)       take = ok < bk;
  else               take = (ov < bv) || (ov == bv && ok < bk);
  if (take) { bv = ov; bk = ok; }
}

// ---- (best, idx, second) triple machinery for margin tracking ----
__device__ static inline bool before3(float a, int ai, float b, int bi) {
  bool na = __builtin_isnan(a), nb = __builtin_isnan(b);
  if (na != nb) return na;
  if (na)       return ai < bi;
  return a < b || (a == b && ai < bi);
}
__device__ static inline float valmin3(float a, float b) {
  if (__builtin_isnan(a) || __builtin_isnan(b)) return __int_as_float(0x7fc00000);
  return fminf(a, b);
}
__device__ static inline void merge3(float ob, int oi, float os,
                                     float& b, int& i, float& s) {
  if (before3(ob, oi, b, i)) { s = valmin3(b, os); b = ob; i = oi; }
  else                        s = valmin3(s, ob);
}

// MFMA distance-GEMM + argmin + margin gate (r20/r21 frozen).
#define LOAD_B(BH, BM, K0) {                                               \
  size_t rowoff_ = (size_t)(colbase + l15) * DIM + (K0) + l4 * 8;          \
  _Pragma("unroll")                                                        \
  for (int j_ = 0; j_ < 4; j_++) {                                         \
    size_t off_ = rowoff_ + (size_t)j_ * 16 * DIM;                         \
    BH[j_] = *reinterpret_cast<const bf16x8*>(&ch[off_]);                  \
    BM[j_] = *reinterpret_cast<const bf16x8*>(&cm[off_]);                  \
  } }

#define PREFETCH_A(K0) {                                                   \
  v0 = *reinterpret_cast<const float4*>(srcbase + (K0));                   \
  v1 = *reinterpret_cast<const float4*>(srcbase + (K0) + 4); }

#define WRITE_A(BUF) {                                                     \
  float vv_[8] = {v0.x, v0.y, v0.z, v0.w, v1.x, v1.y, v1.z, v1.w};         \
  bf16x8 vh_, vm_;                                                         \
  _Pragma("unroll")                                                        \
  for (int q_ = 0; q_ < 8; q_++) {                                         \
    ushort h_, m_;                                                         \
    split2(vv_[q_], h_, m_);                                               \
    vh_[q_] = (short)h_; vm_[q_] = (short)m_;                              \
  }                                                                        \
  *reinterpret_cast<bf16x8*>(&ah[BUF][sr][sko]) = vh_;                     \
  *reinterpret_cast<bf16x8*>(&am[BUF][sr][sko]) = vm_; }

#define MFMA_STEP(BUF, BH, BM)                                             \
  _Pragma("unroll")                                                        \
  for (int i_ = 0; i_ < 4; i_++) {                                         \
    int r_ = i_ * 16 + l15, ko_ = l4 * 8;                                  \
    bf16x8 fah_ = *reinterpret_cast<bf16x8*>(&ah[BUF][r_][ko_]);           \
    bf16x8 fam_ = *reinterpret_cast<bf16x8*>(&am[BUF][r_][ko_]);           \
    _Pragma("unroll")                                                      \
    for (int j_ = 0; j_ < 4; j_++) {                                       \
      acc[i_][j_] = __builtin_amdgcn_mfma_f32_16x16x32_bf16(fah_, BH[j_], acc[i_][j_], 0, 0, 0); \
      acc[i_][j_] = __builtin_amdgcn_mfma_f32_16x16x32_bf16(fah_, BM[j_], acc[i_][j_], 0, 0, 0); \
      acc[i_][j_] = __builtin_amdgcn_mfma_f32_16x16x32_bf16(fam_, BH[j_], acc[i_][j_], 0, 0, 0); \
    } }

#define LDS_BARRIER() do {                                                 \
  asm volatile("s_waitcnt lgkmcnt(0)" ::: "memory");                       \
  __builtin_amdgcn_s_barrier();                                            \
} while (0)

__launch_bounds__(256, 4)
__global__ void assign_mfma_kernel(const float* __restrict__ x,
                                   const ushort* __restrict__ ch,
                                   const ushort* __restrict__ cm,
                                   const float* __restrict__ cnorm,
                                   int* __restrict__ assign,
                                   int* __restrict__ ambigCount,
                                   int* __restrict__ ambigList) {
  __shared__ __align__(16) ushort ah[2][64][40], am[2][64][40];   // 20.5 KB
  __shared__ float  redv[4][64];
  __shared__ int    redi[4][64];
  __shared__ float  reds[4][64];

  const int t = threadIdx.x;
  const int w = t >> 6;
  const int lane = t & 63;
  const int m0 = blockIdx.x * BM;
  const int colbase = w * 64;
  const int l15 = lane & 15, l4 = lane >> 4;
  const int sr = t >> 2, sko = (t & 3) * 8;        // staging map
  const float* srcbase = &x[(size_t)(m0 + sr) * DIM + sko];

  f32x4 acc[4][4];
#pragma unroll
  for (int i = 0; i < 4; i++)
#pragma unroll
    for (int j = 0; j < 4; j++) acc[i][j] = (f32x4)(0.f);

  bf16x8 bhA[4], bmA[4], bhB[4], bmB[4];
  float4 v0, v1;

  // prologue: stage A(k=0) into buf 0; load B(k=0) into set A
  PREFETCH_A(0);
  WRITE_A(0);
  LOAD_B(bhA, bmA, 0);
  __syncthreads();

#pragma unroll
  for (int ks2 = 0; ks2 < 16; ks2 += 2) {
    const int k0 = ks2 * 32;
    // ---- even step (ks = ks2): A in buf0, B in set A ----
    PREFETCH_A(k0 + 32);                 // A for ks2+1 (always exists)
    LOAD_B(bhB, bmB, k0 + 32);           // B for ks2+1, issued BEFORE MFMAs
    MFMA_STEP(0, bhA, bmA);
    WRITE_A(1);
    LDS_BARRIER();                       // vmcnt stays in flight
    // ---- odd step (ks = ks2+1): A in buf1, B in set B ----
    if (ks2 + 2 < 16) {
      PREFETCH_A(k0 + 64);
      LOAD_B(bhA, bmA, k0 + 64);
    }
    MFMA_STEP(1, bhB, bmB);
    if (ks2 + 2 < 16) WRITE_A(0);
    LDS_BARRIER();
  }

  // ---- epilogue: d2 = cnorm - 2*dot; (best, idx, second); margin gate ----
  {
#pragma clang fp contract(off)
    float cn[4];
#pragma unroll
    for (int j = 0; j < 4; j++) cn[j] = cnorm[colbase + j * 16 + l15];

#pragma unroll
    for (int i = 0; i < 4; i++) {
#pragma unroll
      for (int reg = 0; reg < 4; reg++) {
        float bb = __int_as_float(0x7f800000);  // +inf
        int   bi = 0x7fffffff;
        float bs = __int_as_float(0x7f800000);
#pragma unroll
        for (int j = 0; j < 4; j++) {
          int col = colbase + j * 16 + l15;
          float d2 = cn[j] - 2.0f * acc[i][j][reg];
          merge3(d2, col, __int_as_float(0x7f800000), bb, bi, bs);
        }
#pragma unroll
        for (int s = 1; s < 16; s <<= 1) {
          float ob = __shfl_xor(bb, s);
          int   oi = __shfl_xor(bi, s);
          float os = __shfl_xor(bs, s);
          merge3(ob, oi, os, bb, bi, bs);
        }
        if (l15 == 0) {
          int row = i * 16 + l4 * 4 + reg;
          redv[w][row] = bb; redi[w][row] = bi; reds[w][row] = bs;
        }
      }
    }
    __syncthreads();
    if (t < 64) {
      float bb = __int_as_float(0x7f800000);
      int   bi = 0x7fffffff;
      float bs = __int_as_float(0x7f800000);
#pragma unroll
      for (int w2 = 0; w2 < 4; w2++)
        merge3(redv[w2][t], redi[w2][t], reds[w2][t], bb, bi, bs);
      assign[m0 + t] = bi;
      float margin = bs - bb;
      if (!(margin > TAU)) {                 // NaN margin also flags
        int pos = atomicAdd(ambigCount, 1);
        if (pos < N_PTS) ambigList[pos] = m0 + t;
      }
    }
  }
}

// Exact recheck of ambiguous points with the r5 bit-exact scheme.
__launch_bounds__(256)
__global__ void refine_kernel(const float* __restrict__ x,
                              const float* __restrict__ ctr,
                              const float* __restrict__ cnorm,
                              const int* __restrict__ ambigList,
                              const int* __restrict__ ambigCount,
                              int* __restrict__ assign) {
  __shared__ float xrow[DIM];
  __shared__ float cs[K_CL][33];
  __shared__ float rv[K_CL];
  __shared__ int   ri[K_CL];
  const int t = threadIdx.x;
  int cnt = *ambigCount; if (cnt > N_PTS) cnt = N_PTS;
  for (int a = blockIdx.x; a < cnt; a += gridDim.x) {
    int pt = ambigList[a];
    __syncthreads();
    for (int u = t; u < DIM; u += 256) xrow[u] = x[(size_t)pt * DIM + u];
    float accA = 0.f, accB = 0.f;
    for (int c = 0; c < 16; c++) {
      __syncthreads();
      for (int u = t; u < K_CL * 32; u += 256) {
        int k = u >> 5, j = u & 31;
        cs[k][j] = ctr[(size_t)k * DIM + c * 32 + j];
      }
      __syncthreads();
      {
#pragma clang fp contract(off)
        float s = (c < 9) ? accA : accB;
        for (int j = 0; j < 32; j++) {
          float pv = xrow[c * 32 + j] * cs[t][j];
          s = s + pv;
        }
        if (c < 9) accA = s; else accB = s;
      }
    }
    float d2;
    {
#pragma clang fp contract(off)
      float dot = accA + accB;
      float tw = 2.0f * dot;
      d2 = cnorm[t] - tw;
    }
    rv[t] = d2; ri[t] = t;
    __syncthreads();
    for (int st = 128; st >= 1; st >>= 1) {
      if (t < st) argmin_pick(rv[t + st], ri[t + st], rv[t], ri[t]);
      __syncthreads();
    }
    if (t == 0) assign[pt] = ri[0];
  }
}

// Counting sort stage 1: per-block histogram, BLOCK-major output (coalesced).
__global__ void hist_kernel(const int* __restrict__ assign, int* __restrict__ blockHist) {
  __shared__ int h[K_CL];
  int b = blockIdx.x, t = threadIdx.x;
  h[t] = 0; __syncthreads();
  int k = assign[b * 256 + t];
  atomicAdd(&h[k], 1);
  __syncthreads();
  blockHist[b * 256 + t] = h[t];
}

// Stage 2a: per-cluster exclusive scan over the 256 block values (parallel).
__global__ void scan_blocks_kernel(int* __restrict__ blockHist,
                                   int* __restrict__ counts) {
  __shared__ int v[256];
  int k = blockIdx.x, b = threadIdx.x;
  int x = blockHist[b * 256 + k];
  v[b] = x;
  __syncthreads();
  for (int s = 1; s < 256; s <<= 1) {
    int add = (b >= s) ? v[b - s] : 0;
    __syncthreads();
    v[b] += add;
    __syncthreads();
  }
  blockHist[b * 256 + k] = v[b] - x;
  if (b == 255) counts[k] = v[255];
}

// Stage 2b: exclusive scan of cluster totals -> clusterStart. One block.
__global__ void scan_clusters_kernel(const int* __restrict__ counts,
                                     int* __restrict__ clusterStart) {
  __shared__ int v[256];
  int k = threadIdx.x;
  int x = counts[k];
  v[k] = x;
  __syncthreads();
  for (int s = 1; s < 256; s <<= 1) {
    int add = (k >= s) ? v[k - s] : 0;
    __syncthreads();
    v[k] += add;
    __syncthreads();
  }
  clusterStart[k] = v[k] - x;
}

// Stage 3: stable scatter via ballot ranking (r21 proven).
__global__ void scatter_kernel(const int* __restrict__ assign,
                               const int* __restrict__ blockHist,
                               const int* __restrict__ clusterStart,
                               int* __restrict__ sortedIdx) {
  __shared__ int whist[4][K_CL];               // per-wave key counts
  int b = blockIdx.x, t = threadIdx.x;
  int w = t >> 6, lane = t & 63;
  int n = b * 256 + t;
  int k = assign[n];
  for (int u = t; u < 4 * K_CL; u += 256) (&whist[0][0])[u] = 0;
  __syncthreads();
  unsigned long long same = ~0ULL;
#pragma unroll
  for (int bit = 0; bit < 8; bit++) {
    unsigned long long m = __ballot((k >> bit) & 1);
    same &= ((k >> bit) & 1) ? m : ~m;
  }
  unsigned long long below = same & ((lane == 0) ? 0ULL : ((~0ULL) >> (64 - lane)));
  int rank_in_wave = __popcll(below);
  if (rank_in_wave == 0) whist[w][k] = __popcll(same);   // one writer per key
  __syncthreads();
  int rank = rank_in_wave;
  for (int w2 = 0; w2 < w; w2++) rank += whist[w2][k];
  sortedIdx[clusterStart[k] + blockHist[b * 256 + k] + rank] = n;
}

// Stage 4a: per-(cluster, chunk) partial sums, nch chunks per cluster.
__global__ void segsum_part_kernel(const float* __restrict__ x,
                                   const int* __restrict__ sortedIdx,
                                   const int* __restrict__ clusterStart,
                                   const int* __restrict__ counts,
                                   float* __restrict__ part, int nch) {
#pragma clang fp contract(off)
  int k = blockIdx.x / nch;      // cluster
  int c = blockIdx.x - k * nch;  // chunk
  int d = threadIdx.x;
  int start = clusterStart[k], cnt = counts[k];
  int ch = (cnt + nch - 1) / nch;
  int b0 = c * ch;
  int b1 = b0 + ch; if (b1 > cnt) b1 = cnt;
  float s = 0.f;
  for (int i = b0; i < b1; i++) {
    int idx = sortedIdx[start + i];
    s = s + x[(size_t)idx * DIM + d];
  }
  part[((size_t)k * nch + c) * DIM + d] = s;
}

// Stage 4b (last iter): combine chunks ascending, divide -> out.
__global__ void segsum_final_kernel(const float* __restrict__ part,
                                    const int* __restrict__ counts,
                                    float* __restrict__ out, int nch) {
#pragma clang fp contract(off)
  int k = blockIdx.x, d = threadIdx.x;
  float s = 0.f;
  for (int c = 0; c < nch; c++)
    s = s + part[((size_t)k * nch + c) * DIM + d];
  out[k * DIM + d] = s / (float)counts[k];   // cnt==0 -> NaN, matches ref
}

// Stage 4b + prep fused (iters 0..ITERS-2): combine chunks -> next centers,
// split to bf16 planes, cnorm (same strict-sequential order), zero ambig.
__global__ void update_kernel(const float* __restrict__ part,
                              const int* __restrict__ counts,
                              float* __restrict__ ctrNext,
                              float* __restrict__ cnorm,
                              int* __restrict__ ambigCount,
                              ushort* __restrict__ ch,
                              ushort* __restrict__ cm, int nch) {
  __shared__ float row[DIM];
  const int k = blockIdx.x, t = threadIdx.x;   // 512 threads, t = dim
  {
#pragma clang fp contract(off)
    float s = 0.f;
    for (int c = 0; c < nch; c++)
      s = s + part[((size_t)k * nch + c) * DIM + t];
    float mean = s / (float)counts[k];         // cnt==0 -> NaN, matches ref
    ctrNext[(size_t)k * DIM + t] = mean;
    row[t] = mean;
  }
  {
    ushort h, m;
    split2(row[t], h, m);
    ch[(size_t)k * DIM + t] = h;
    cm[(size_t)k * DIM + t] = m;
  }
  __syncthreads();
  if (t == 0) {
#pragma clang fp contract(off)
    float s = 0.f;
    for (int j = 0; j < DIM; j++) {
      float v = row[j];
      float p = v * v;
      s = s + p;
    }
    cnorm[k] = s;
  }
  if (t == 1 && k == 0) *ambigCount = 0;
}

// ---------------- host ----------------
// Both sorts batched: identical comparison network per array, run together.
static inline void run_sort2(unsigned long long* dA, unsigned long long* dB,
                             hipStream_t stream) {
  bitonic_local_start2<<<64, 1024, 0, stream>>>(dA, dB);
  for (int k = 4096; k <= 65536; k <<= 1) {
    for (int j = k >> 1; j >= 2048; j >>= 1)
      bitonic_global_step2<<<256, 256, 0, stream>>>(dA, dB, k, j);
    bitonic_local2<<<64, 1024, 0, stream>>>(dA, dB, k);
  }
}

extern "C" void kernel_launch(void* const* d_in, const int* in_sizes, int n_in,
                              void* d_out, int out_size, void* d_ws, size_t ws_size,
                              hipStream_t stream) {
  const float* x = (const float*)d_in[0];
  float* out = (float*)d_out;

  char* p = (char*)d_ws;
  size_t used = 0;
  auto alloc = [&](size_t bytes) {
    char* r = p;
    size_t rb = (bytes + 255) & ~(size_t)255;
    p += rb; used += rb;
    return r;
  };
  unsigned long long* keyA = (unsigned long long*)alloc(N_PTS * 8);
  unsigned long long* keyB = (unsigned long long*)alloc(N_PTS * 8);
  uint32_t* perm1          = (uint32_t*)alloc(N_PTS * 4);
  int* assign              = (int*)alloc(N_PTS * 4);
  int* blockHist           = (int*)alloc(K_CL * 256 * 4);
  int* clusterStart        = (int*)alloc(K_CL * 4);
  int* counts              = (int*)alloc(K_CL * 4);
  int* sortedIdx           = (int*)alloc(N_PTS * 4);
  float* ctrA              = (float*)alloc(K_CL * DIM * 4);
  float* ctrB              = (float*)alloc(K_CL * DIM * 4);
  float* cnorm             = (float*)alloc(K_CL * 4);
  ushort* ch               = (ushort*)alloc((size_t)K_CL * DIM * 2);
  ushort* cm               = (ushort*)alloc((size_t)K_CL * DIM * 2);
  int* ambigCount          = (int*)alloc(4);
  int* ambigList           = (int*)alloc(N_PTS * 4);

  // Chunk count for segsum: 64 if workspace allows, else 8.
  const size_t part64 = (size_t)K_CL * 64 * DIM * 4;   // 33.5 MB
  int nch = (ws_size >= used + part64 + 256) ? 64 : 8;
  float* part = (float*)alloc((size_t)K_CL * nch * DIM * 4);

  // Partitionable (foldlike) threefry split: split(key)[j] = hash(key,(0,j)).
  uint32_t k1a, k1b, s1a, s1b;
  tf2x32(0u, 1u, 0u, 0u, &k1a, &k1b);
  tf2x32(0u, 1u, 0u, 1u, &s1a, &s1b);
  uint32_t k2a, k2b, s2a, s2b;
  tf2x32(k1a, k1b, 0u, 0u, &k2a, &k2b);
  tf2x32(k1a, k1b, 0u, 1u, &s2a, &s2b);

  genbits2_kernel<<<512, 256, 0, stream>>>(keyA, keyB, s1a, s1b, s2a, s2b);
  run_sort2(keyA, keyB, stream);
  extract_low_kernel<<<256, 256, 0, stream>>>(keyA, perm1);
  init_centers_kernel<<<K_CL, DIM, 0, stream>>>(keyB, perm1, x, ctrA);
  prep_kernel<<<K_CL, 256, 0, stream>>>(ctrA, cnorm, ambigCount, ch, cm);

  float* cur = ctrA;
  for (int it = 0; it < ITERS; ++it) {
    assign_mfma_kernel<<<N_PTS / BM, 256, 0, stream>>>(x, ch, cm, cnorm, assign,
                                                       ambigCount, ambigList);
    refine_kernel<<<256, 256, 0, stream>>>(x, cur, cnorm, ambigList, ambigCount, assign);
    hist_kernel<<<256, 256, 0, stream>>>(assign, blockHist);
    scan_blocks_kernel<<<256, 256, 0, stream>>>(blockHist, counts);
    scan_clusters_kernel<<<1, 256, 0, stream>>>(counts, clusterStart);
    scatter_kernel<<<256, 256, 0, stream>>>(assign, blockHist, clusterStart, sortedIdx);
    segsum_part_kernel<<<K_CL * nch, DIM, 0, stream>>>(x, sortedIdx, clusterStart,
                                                       counts, part, nch);
    if (it < ITERS - 1) {
      float* next = (it & 1) ? ctrA : ctrB;
      update_kernel<<<K_CL, DIM, 0, stream>>>(part, counts, next, cnorm,
                                              ambigCount, ch, cm, nch);
      cur = next;
    } else {
      segsum_final_kernel<<<K_CL, DIM, 0, stream>>>(part, counts, out, nch);
    }
  }
}